// Round 1
// baseline (234.341 us; speedup 1.0000x reference)
//
#include <hip/hip_runtime.h>
#include <math.h>

#define B 16
#define L 128
#define H 100
#define P 20
#define CH 210
#define EPSF 1e-8f
#define PADW 52   // h-half row stride in LDS: 50 data + 2 zero pad; 52*4B = 16B multiple

// workspace layout (floats):
//  cosbuf : 0        size 2*B*L*L = 524288   [dir][b][i][j]
//  rowsum : 524288   size 2*B*L   = 4096     sum_j cos  (att_mean_h denom)
//  colsum : 528384   size 2*B*L   = 4096     sum_i cos  (att_mean_p denom)
//  lastv  : 532480   size 4*B*H   = 6400     [p_fw,p_bw,h_fw,h_bw][b][h]
//  attbuf : 538880   size 8*B*L*H = 1638400  [(side*2+kind)*2+dir][b][r][h]
//  total ~8.7 MB

// ---------------- prep: lengths -> last vectors ----------------
__global__ __launch_bounds__(128) void prep_kernel(
    const float* __restrict__ ctx_p, const int* __restrict__ mask_p,
    const float* __restrict__ ctx_h, const int* __restrict__ mask_h,
    float* __restrict__ lastv)
{
    const int b = blockIdx.x, is_h = blockIdx.y, t = threadIdx.x;
    const float* ctx = is_h ? ctx_h : ctx_p;
    const int* mask = is_h ? mask_h : mask_p;
    __shared__ int sm[L];
    sm[t] = mask[b*L + t];
    __syncthreads();
    for (int s = 64; s > 0; s >>= 1) {
        if (t < s) sm[t] += sm[t + s];
        __syncthreads();
    }
    int last = sm[0] - 1;
    if (last < 0) last = 0;
    if (t < H) {
        // fw last = row[last], bw "last" = row 0 (reference takes [:,0:1,:])
        lastv[((size_t)(is_h*2 + 0)*B + b)*H + t] = ctx[(size_t)(b*L + last)*(2*H) + t];
        lastv[((size_t)(is_h*2 + 1)*B + b)*H + t] = ctx[(size_t)(b*L + 0)*(2*H) + H + t];
    }
}

// ---------------- unified pairwise kernel ----------------
// grid (B, 2 dirs, 21): p<20 -> mpm_pairwise perspective p (params[2] fw / params[3] bw),
// p==20 -> unweighted cosine_pairwise: also writes cos matrix, rowsum/colsum, out ch 0-3.
// Both use div_safe(n, n1*n2) = n / max(n1*n2, eps)  -- identical formula.
__global__ __launch_bounds__(256) void pair_kernel(
    const float* __restrict__ ctx_p, const float* __restrict__ ctx_h,
    const float* __restrict__ params,
    float* __restrict__ cosbuf, float* __restrict__ rowsum,
    float* __restrict__ colsum, float* __restrict__ out)
{
    const int b = blockIdx.x, dir = blockIdx.y, p = blockIdx.z;
    const int off = dir ? H : 0;
    const int t = threadIdx.x;

    __shared__ union {
        struct { float aw[L][PADW]; float bw[L][PADW]; } s;  // 53248 B
        float red[4][16][L];                                 // 32768 B (rmax,rsum,cmax,csum)
    } u;
    __shared__ float wshh[2][PADW];
    __shared__ float wn1s[L], wn2s[L];

    // stage weights for both h-halves, zero the 2-float pad
    if (t < 2*PADW) {
        int half = t / PADW, hc = t - half*PADW;
        float w = 0.f;
        if (hc < 50) {
            int h = half*50 + hc;
            w = (p == P) ? 1.f : params[((size_t)((dir ? 3 : 2)*P + p))*H + h];
        }
        wshh[half][hc] = w;
    }

    const int ti = t & 15, tj = t >> 4;
    float acc[8][8];
#pragma unroll
    for (int r = 0; r < 8; ++r)
#pragma unroll
        for (int c = 0; c < 8; ++c) acc[r][c] = 0.f;
    float nsq = 0.f;

    for (int half = 0; half < 2; ++half) {
        __syncthreads();   // half0: covers wshh staging; half1: protect restage
        // stage weighted tiles aw = w*p_dir rows, bw = w*h_dir rows (float2, 8B-aligned safe)
        for (int e = t; e < 2*26*L; e += 256) {
            int which = (e >= 26*L);
            int e2 = which ? e - 26*L : e;
            int row = e2 / 26, g = e2 - row*26;
            float2 v;
            if (g < 25) {
                const float* src = (which ? ctx_h : ctx_p)
                    + (size_t)(b*L + row)*(2*H) + off + half*50 + 2*g;
                v = *(const float2*)src;
            } else { v.x = 0.f; v.y = 0.f; }
            float2 w2 = *(const float2*)&wshh[half][2*g];
            float2 o; o.x = v.x*w2.x; o.y = v.y*w2.y;
            *(float2*)(which ? &u.s.bw[row][2*g] : &u.s.aw[row][2*g]) = o;
        }
        __syncthreads();
        // norm partial sums: t<128 -> row t of aw, t>=128 -> row t-128 of bw
        {
            int i = t & 127;
            const float* rowptr = (t < L) ? u.s.aw[i] : u.s.bw[i];
#pragma unroll
            for (int g = 0; g < 13; ++g) {
                float4 v = *(const float4*)&rowptr[4*g];
                nsq += v.x*v.x + v.y*v.y + v.z*v.z + v.w*v.w;
            }
        }
        // main: 8x8 register tile, rows i = ti+16r, cols j = tj+16c (stride-16 grouping
        // keeps float4 LDS reads at worst 2-way bank aliasing with 52-float row stride)
        for (int g = 0; g < 13; ++g) {
            float4 a4[8];
#pragma unroll
            for (int r = 0; r < 8; ++r) a4[r] = *(const float4*)&u.s.aw[ti + 16*r][4*g];
#pragma unroll
            for (int c = 0; c < 8; ++c) {
                float4 b4 = *(const float4*)&u.s.bw[tj + 16*c][4*g];
#pragma unroll
                for (int r = 0; r < 8; ++r) {
                    acc[r][c] = fmaf(a4[r].x, b4.x, acc[r][c]);
                    acc[r][c] = fmaf(a4[r].y, b4.y, acc[r][c]);
                    acc[r][c] = fmaf(a4[r].z, b4.z, acc[r][c]);
                    acc[r][c] = fmaf(a4[r].w, b4.w, acc[r][c]);
                }
            }
        }
    }
    // publish norms
    {
        float n = sqrtf(nsq);
        if (t < L) wn1s[t] = n; else wn2s[t & 127] = n;
    }
    __syncthreads();   // after this, u.s is dead -> u.red may be reused

    float rmax[8], rsum[8], cmax[8], csum[8];
#pragma unroll
    for (int r = 0; r < 8; ++r) { rmax[r] = -INFINITY; rsum[r] = 0.f; }
#pragma unroll
    for (int c = 0; c < 8; ++c) { cmax[c] = -INFINITY; csum[c] = 0.f; }
    const bool iscos = (p == P);
    float* cosm = cosbuf + ((size_t)dir*B + b)*L*L;
#pragma unroll
    for (int r = 0; r < 8; ++r) {
        int i = ti + 16*r;
        float n1 = wn1s[i];
#pragma unroll
        for (int c = 0; c < 8; ++c) {
            int j = tj + 16*c;
            float mval = acc[r][c] / fmaxf(n1 * wn2s[j], EPSF);
            if (iscos) cosm[i*L + j] = mval;
            rmax[r] = fmaxf(rmax[r], mval); rsum[r] += mval;
            cmax[c] = fmaxf(cmax[c], mval); csum[c] += mval;
        }
    }
#pragma unroll
    for (int r = 0; r < 8; ++r) {
        u.red[0][tj][ti + 16*r] = rmax[r];
        u.red[1][tj][ti + 16*r] = rsum[r];
    }
#pragma unroll
    for (int c = 0; c < 8; ++c) {
        u.red[2][ti][tj + 16*c] = cmax[c];
        u.red[3][ti][tj + 16*c] = csum[c];
    }
    __syncthreads();

    int chmax, chmean;
    if (p < P) { chmax = (dir ? 86 : 46) + p; chmean = (dir ? 106 : 66) + p; }
    else       { chmax = dir*2;              chmean = dir*2 + 1; }

    if (t < L) {   // row reductions -> mv_p
        float mx = -INFINITY, smv = 0.f;
#pragma unroll
        for (int q = 0; q < 16; ++q) { mx = fmaxf(mx, u.red[0][q][t]); smv += u.red[1][q][t]; }
        float* mvp = out + (size_t)(b*L + t)*CH;
        mvp[chmax] = mx; mvp[chmean] = smv * (1.f/L);
        if (iscos) rowsum[(dir*B + b)*L + t] = smv;
    } else {       // col reductions -> mv_h
        int j = t & 127;
        float mx = -INFINITY, smv = 0.f;
#pragma unroll
        for (int q = 0; q < 16; ++q) { mx = fmaxf(mx, u.red[2][q][j]); smv += u.red[3][q][j]; }
        float* mvh = out + (size_t)B*L*CH + (size_t)(b*L + j)*CH;
        mvh[chmax] = mx; mvh[chmean] = smv * (1.f/L);
        if (iscos) colsum[(dir*B + b)*L + j] = smv;
    }
}

// ---------------- attention vectors (mean & max) ----------------
// grid (B, dir*2+side, rc*2+hh): side0 -> att_*_h_dir (reduce over j, out per i),
// side1 -> att_*_p_dir (reduce over i, out per j). rc: 32-row chunk, hh: 50-h half.
__global__ __launch_bounds__(256) void att_kernel(
    const float* __restrict__ ctx_p, const float* __restrict__ ctx_h,
    const float* __restrict__ cosbuf, const float* __restrict__ rowsum,
    const float* __restrict__ colsum, float* __restrict__ attbuf)
{
    const int b = blockIdx.x;
    const int dir = blockIdx.y >> 1, side = blockIdx.y & 1;
    const int rc = blockIdx.z >> 1, hh = blockIdx.z & 1;
    const int r0 = rc * 32;
    const int off = (dir ? H : 0) + hh*50;
    const int t = threadIdx.x;

    __shared__ float sv[L][PADW];   // source vectors (h- or p-side), zero padded to 52
    __shared__ float cvT[L][36];    // cvT[s][r]: cos slice transposed for float2 reads

    const float* cm = cosbuf + ((size_t)dir*B + b)*L*L;
    const float* src = side ? ctx_p : ctx_h;

    for (int e = t; e < 26*L; e += 256) {
        int s = e / 26, g = e - s*26;
        float2 v;
        if (g < 25) v = *(const float2*)(src + (size_t)(b*L + s)*(2*H) + off + 2*g);
        else { v.x = 0.f; v.y = 0.f; }
        *(float2*)&sv[s][2*g] = v;
    }
    for (int e = t; e < 32*L; e += 256) {
        int r = e & 31, s = e >> 5;
        cvT[s][r] = side ? cm[s*L + (r0 + r)] : cm[(r0 + r)*L + s];
    }
    __syncthreads();

    const int tr = t & 15, th = t >> 4;
    if (th < 13) {
        float acc[2][4], amx[2][4];
#pragma unroll
        for (int rr = 0; rr < 2; ++rr)
#pragma unroll
            for (int q = 0; q < 4; ++q) { acc[rr][q] = 0.f; amx[rr][q] = -INFINITY; }
        for (int s = 0; s < L; ++s) {
            float2 c2 = *(const float2*)&cvT[s][2*tr];
            float4 v4 = *(const float4*)&sv[s][4*th];
            float cs[2] = {c2.x, c2.y};
            float vs[4] = {v4.x, v4.y, v4.z, v4.w};
#pragma unroll
            for (int rr = 0; rr < 2; ++rr)
#pragma unroll
                for (int q = 0; q < 4; ++q) {
                    float pr = cs[rr] * vs[q];
                    acc[rr][q] += pr;
                    amx[rr][q] = fmaxf(amx[rr][q], pr);
                }
        }
        const float* den = side ? colsum : rowsum;
#pragma unroll
        for (int rr = 0; rr < 2; ++rr) {
            int rg = r0 + 2*tr + rr;
            float d = fmaxf(den[(dir*B + b)*L + rg], EPSF);
            float* meanp = attbuf + ((((size_t)side*2 + 0)*2 + dir)*B*L + (b*L + rg))*H + hh*50;
            float* maxp  = attbuf + ((((size_t)side*2 + 1)*2 + dir)*B*L + (b*L + rg))*H + hh*50;
#pragma unroll
            for (int q = 0; q < 4; ++q) {
                int hl = 4*th + q;
                if (hl < 50) { meanp[hl] = acc[rr][q] / d; maxp[hl] = amx[rr][q]; }
            }
        }
    }
}

// ---------------- pointwise mpm (mv1 + 20 mvp channels) ----------------
// grid (B, side, m in 0..5): m0/1 last-vec, m2/3 att_mean, m4/5 att_max (fw/bw alternating).
// v1,v2 held in VGPRs; weight rows are wave-uniform -> scalar loads.
__global__ __launch_bounds__(128) void point_kernel(
    const float* __restrict__ ctx_p, const float* __restrict__ ctx_h,
    const float* __restrict__ params,
    const float* __restrict__ lastv, const float* __restrict__ attbuf,
    float* __restrict__ out)
{
    const int b = blockIdx.x, side = blockIdx.y, m = blockIdx.z;
    const int dir = m & 1;
    const int wsel_[6] = {0, 1, 4, 5, 6, 7};
    const int chb_[6] = {4, 25, 126, 147, 168, 189};
    const int i = threadIdx.x;
    const int off = dir ? H : 0;

    const float* v1p = (side ? ctx_h : ctx_p) + (size_t)(b*L + i)*(2*H) + off;
    const float* v2p;
    if (m < 2) {
        v2p = lastv + ((size_t)((side ? 0 : 2) + dir)*B + b)*H;   // opposite side's last vec
    } else {
        int kind = (m >= 4) ? 1 : 0;   // mean / max
        v2p = attbuf + ((((size_t)side*2 + kind)*2 + dir)*B*L + (b*L + i))*H;
    }

    float v1[H], v2[H];
#pragma unroll
    for (int g = 0; g < 25; ++g) {
        float4 x = *(const float4*)(v1p + 4*g);
        v1[4*g] = x.x; v1[4*g+1] = x.y; v1[4*g+2] = x.z; v1[4*g+3] = x.w;
        float4 y = *(const float4*)(v2p + 4*g);
        v2[4*g] = y.x; v2[4*g+1] = y.y; v2[4*g+2] = y.z; v2[4*g+3] = y.w;
    }

    float* orow = out + (size_t)side*B*L*CH + (size_t)(b*L + i)*CH;

    {   // unweighted cos_sim: dot / (max(n1,eps)*max(n2,eps))
        float s11 = 0.f, s22 = 0.f, s12 = 0.f;
#pragma unroll
        for (int h = 0; h < H; ++h) {
            s11 = fmaf(v1[h], v1[h], s11);
            s22 = fmaf(v2[h], v2[h], s22);
            s12 = fmaf(v1[h], v2[h], s12);
        }
        orow[chb_[m]] = s12 / (fmaxf(sqrtf(s11), EPSF) * fmaxf(sqrtf(s22), EPSF));
    }
    const float* wb = params + (size_t)wsel_[m]*P*H;
    for (int k = 0; k < P; ++k) {
        float s11 = 0.f, s22 = 0.f, s12 = 0.f;
#pragma unroll
        for (int h = 0; h < H; ++h) {
            float w = wb[k*H + h];   // wave-uniform -> SGPR load
            float a = w * v1[h], c = w * v2[h];
            s11 = fmaf(a, a, s11);
            s22 = fmaf(c, c, s22);
            s12 = fmaf(a, c, s12);
        }
        orow[chb_[m] + 1 + k] = s12 / (fmaxf(sqrtf(s11), EPSF) * fmaxf(sqrtf(s22), EPSF));
    }
}

extern "C" void kernel_launch(void* const* d_in, const int* in_sizes, int n_in,
                              void* d_out, int out_size, void* d_ws, size_t ws_size,
                              hipStream_t stream) {
    const float* ctx_p  = (const float*)d_in[0];
    const int*   mask_p = (const int*)d_in[1];
    const float* ctx_h  = (const float*)d_in[2];
    const int*   mask_h = (const int*)d_in[3];
    const float* params = (const float*)d_in[4];
    float* out = (float*)d_out;

    float* ws     = (float*)d_ws;           // needs ~8.7 MB
    float* cosbuf = ws;
    float* rowsum = ws + 524288;
    float* colsum = ws + 528384;
    float* lastv  = ws + 532480;
    float* attbuf = ws + 538880;

    prep_kernel <<<dim3(B, 2),     128, 0, stream>>>(ctx_p, mask_p, ctx_h, mask_h, lastv);
    pair_kernel <<<dim3(B, 2, 21), 256, 0, stream>>>(ctx_p, ctx_h, params,
                                                     cosbuf, rowsum, colsum, out);
    att_kernel  <<<dim3(B, 4, 8),  256, 0, stream>>>(ctx_p, ctx_h, cosbuf,
                                                     rowsum, colsum, attbuf);
    point_kernel<<<dim3(B, 2, 6),  128, 0, stream>>>(ctx_p, ctx_h, params,
                                                     lastv, attbuf, out);
}

// Round 2
// 179.531 us; speedup vs baseline: 1.3053x; 1.3053x over previous
//
#include <hip/hip_runtime.h>
#include <math.h>

#define B 16
#define L 128
#define H 100
#define P 20
#define CH 210
#define EPSF 1e-8f

// workspace layout (float offsets), total ~22.6 MB
#define OFF_COS    0u         // [dir][b][i][j]            524288
#define OFF_COST   524288u    // [dir][b][j][i]            524288
#define OFF_ROWSUM 1048576u   // [dir][b][i]               4096
#define OFF_COLSUM 1052672u   // [dir][b][j]               4096
#define OFF_LASTV  1056768u   // [is_h*2+dir][b][h]        6400
#define OFF_W2T    1063168u   // [m8][g25][hh4][p21] w^2   16800 (p==20 -> 1.0)
#define OFF_NBUF   1079968u   // [dir][side][b][p21][i]    172032
#define OFF_RPMAX  1252000u   // [dir][b][p21][jt8][i128]  688128
#define OFF_RPSUM  1940128u
#define OFF_CPMAX  2628256u   // [dir][b][p21][it8][j128]
#define OFF_CPSUM  3316384u
#define OFF_ATT    4004512u   // [(side*2+kind)*2+dir][b][r][h] 1638400

// ---------------- prep: lengths -> last vectors ----------------
__global__ __launch_bounds__(128) void prep_kernel(
    const float* __restrict__ ctx_p, const int* __restrict__ mask_p,
    const float* __restrict__ ctx_h, const int* __restrict__ mask_h,
    float* __restrict__ lastv)
{
    const int b = blockIdx.x, is_h = blockIdx.y, t = threadIdx.x;
    const float* ctx = is_h ? ctx_h : ctx_p;
    const int* mask = is_h ? mask_h : mask_p;
    __shared__ int sm[L];
    sm[t] = mask[b*L + t];
    __syncthreads();
    for (int s = 64; s > 0; s >>= 1) {
        if (t < s) sm[t] += sm[t + s];
        __syncthreads();
    }
    int last = sm[0] - 1;
    if (last < 0) last = 0;
    if (t < H) {
        lastv[((size_t)(is_h*2 + 0)*B + b)*H + t] = ctx[(size_t)(b*L + last)*(2*H) + t];
        lastv[((size_t)(is_h*2 + 1)*B + b)*H + t] = ctx[(size_t)(b*L + 0)*(2*H) + H + t];
    }
}

// ---------------- w^2 table: [m][g][hh][p], p==20 -> 1.0 ----------------
__global__ __launch_bounds__(256) void wprep_kernel(
    const float* __restrict__ params, float* __restrict__ w2t)
{
    int e = blockIdx.x*256 + threadIdx.x;
    if (e >= 8*25*4*21) return;
    int m = e / 2100, r = e % 2100;
    int g = r / 84, q = r % 84, hh = q / 21, p = q % 21;
    int h = 4*g + hh;
    float v = 1.f;
    if (p < P) { float w = params[((size_t)m*P + p)*H + h]; v = w*w; }
    w2t[e] = v;   // e == ((m*25+g)*4+hh)*21+p
}

// ---------------- weighted row norms: nbuf[dir][side][b][p][i] ----------------
__global__ __launch_bounds__(128) void norm_kernel(
    const float* __restrict__ ctx_p, const float* __restrict__ ctx_h,
    const float* __restrict__ w2t, float* __restrict__ nbuf)
{
    const int b = blockIdx.x, dir = blockIdx.y, side = blockIdx.z;
    const int i = threadIdx.x;
    const float* row = (side ? ctx_h : ctx_p) + (size_t)(b*L + i)*(2*H) + dir*H;
    const float* wt = w2t + (size_t)(2 + dir)*2100;   // params[2]/params[3]
    float n2[21];
#pragma unroll
    for (int p = 0; p < 21; ++p) n2[p] = 0.f;
    for (int g = 0; g < 25; ++g) {
        float4 v = *(const float4*)(row + 4*g);
        float sq[4] = {v.x*v.x, v.y*v.y, v.z*v.z, v.w*v.w};
        const float* wg = wt + g*84;   // uniform -> s_load
#pragma unroll
        for (int hh = 0; hh < 4; ++hh)
#pragma unroll
            for (int p = 0; p < 21; ++p)
                n2[p] = fmaf(wg[hh*21 + p], sq[hh], n2[p]);
    }
    float* nb = nbuf + ((size_t)((dir*2 + side)*B + b)*21)*128;
#pragma unroll
    for (int p = 0; p < 21; ++p) nb[p*128 + i] = sqrtf(n2[p]);
}

// ---------------- pairwise: all 21 perspectives in one pass ----------------
// grid (B, 2, 64): z = it*8+jt, 16x16 (i,j) tile, thread = one (i,j), acc[21].
__global__ __launch_bounds__(256) void pair_kernel(
    const float* __restrict__ ctx_p, const float* __restrict__ ctx_h,
    const float* __restrict__ w2t, const float* __restrict__ nbuf,
    float* __restrict__ cosbuf, float* __restrict__ cosT,
    float* __restrict__ rpmax, float* __restrict__ rpsum,
    float* __restrict__ cpmax, float* __restrict__ cpsum)
{
    const int b = blockIdx.x, dir = blockIdx.y;
    const int it = blockIdx.z >> 3, jt = blockIdx.z & 7;
    const int t = threadIdx.x;

    __shared__ float aT[16][100];           // stride 100: (100*r)%32=4r -> 2-way max (free)
    __shared__ float bT[16][100];
    __shared__ float nlds[2][21][16];
    __shared__ float rowLDS[2][16][21][2];  // [wj][i_local][p][max,sum]
    __shared__ float colLDS[2][16][21][2];  // [wi][j_local][p][max,sum]

    for (int e = t; e < 800; e += 256) {
        int which = e >= 400;
        int e2 = which ? e - 400 : e;
        int row = e2 / 25, g = e2 - row*25;
        const float* src = (which ? ctx_h : ctx_p)
            + (size_t)(b*L + (which ? jt : it)*16 + row)*(2*H) + dir*H + 4*g;
        float4 v = *(const float4*)src;
        if (which) *(float4*)&bT[row][4*g] = v;
        else       *(float4*)&aT[row][4*g] = v;
    }
    for (int e = t; e < 672; e += 256) {
        int side = e >= 336; int e2 = e - side*336;
        int p = e2 >> 4, ii = e2 & 15;
        nlds[side][p][ii] =
            nbuf[((size_t)((dir*2 + side)*B + b)*21 + p)*128 + (side ? jt : it)*16 + ii];
    }
    __syncthreads();

    const int w = t >> 6, lane = t & 63;
    const int i_sub = lane >> 3, j_sub = lane & 7;
    const int wi = w >> 1, wj = w & 1;
    const int il = wi*8 + i_sub, jl = wj*8 + j_sub;

    float acc[21];
#pragma unroll
    for (int p = 0; p < 21; ++p) acc[p] = 0.f;
    const float* wt = w2t + (size_t)(2 + dir)*2100;
    for (int g = 0; g < 25; ++g) {
        float4 av = *(const float4*)&aT[il][4*g];
        float4 bv = *(const float4*)&bT[jl][4*g];
        float g0 = av.x*bv.x, g1 = av.y*bv.y, g2 = av.z*bv.z, g3 = av.w*bv.w;
        const float* wg = wt + g*84;   // uniform -> s_load, no vector-pipe cost
#pragma unroll
        for (int p = 0; p < 21; ++p) {
            float a = acc[p];
            a = fmaf(wg[p],      g0, a);
            a = fmaf(wg[21 + p], g1, a);
            a = fmaf(wg[42 + p], g2, a);
            a = fmaf(wg[63 + p], g3, a);
            acc[p] = a;
        }
    }

    const int i = it*16 + il, j = jt*16 + jl;
    const size_t cosbase = (size_t)(dir*B + b)*16384;
#pragma unroll
    for (int p = 0; p < 21; ++p) {
        float na = nlds[0][p][il], nb_ = nlds[1][p][jl];
        float mval = acc[p] / fmaxf(na*nb_, EPSF);
        if (p == 20) {
            cosbuf[cosbase + i*128 + j] = mval;
            cosT[cosbase + j*128 + i] = mval;
        }
        float rm = mval, rs = mval;
        rm = fmaxf(rm, __shfl_xor(rm, 1));  rs += __shfl_xor(rs, 1);
        rm = fmaxf(rm, __shfl_xor(rm, 2));  rs += __shfl_xor(rs, 2);
        rm = fmaxf(rm, __shfl_xor(rm, 4));  rs += __shfl_xor(rs, 4);
        float cm = mval, cs = mval;
        cm = fmaxf(cm, __shfl_xor(cm, 8));  cs += __shfl_xor(cs, 8);
        cm = fmaxf(cm, __shfl_xor(cm, 16)); cs += __shfl_xor(cs, 16);
        cm = fmaxf(cm, __shfl_xor(cm, 32)); cs += __shfl_xor(cs, 32);
        if (j_sub == 0) { rowLDS[wj][il][p][0] = rm; rowLDS[wj][il][p][1] = rs; }
        if (i_sub == 0) { colLDS[wi][jl][p][0] = cm; colLDS[wi][jl][p][1] = cs; }
    }
    __syncthreads();
    for (int e = t; e < 1344; e += 256) {
        int rc = e >= 672; int e2 = e - rc*672;
        int ms = e2 & 1; int q = e2 >> 1;
        int ii = q / 21, p = q - ii*21;
        float v0, v1;
        if (rc == 0) { v0 = rowLDS[0][ii][p][ms]; v1 = rowLDS[1][ii][p][ms]; }
        else         { v0 = colLDS[0][ii][p][ms]; v1 = colLDS[1][ii][p][ms]; }
        float v = ms ? (v0 + v1) : fmaxf(v0, v1);
        size_t idx;
        if (rc == 0) idx = (((size_t)(dir*B + b)*21 + p)*8 + jt)*128 + it*16 + ii;
        else         idx = (((size_t)(dir*B + b)*21 + p)*8 + it)*128 + jt*16 + ii;
        float* dst = (rc == 0) ? (ms ? rpsum : rpmax) : (ms ? cpsum : cpmax);
        dst[idx] = v;
    }
}

// ---------------- combine partials -> out channels + rowsum/colsum ----------------
__global__ __launch_bounds__(128) void reduce_kernel(
    const float* __restrict__ rpmax, const float* __restrict__ rpsum,
    const float* __restrict__ cpmax, const float* __restrict__ cpsum,
    float* __restrict__ out, float* __restrict__ rowsum, float* __restrict__ colsum)
{
    const int bd = blockIdx.x, p = blockIdx.y, rc = blockIdx.z;
    const int dir = bd >> 4, b = bd & 15;
    const int t = threadIdx.x;
    const float* pm = rc ? cpmax : rpmax;
    const float* ps = rc ? cpsum : rpsum;
    size_t base = (((size_t)bd*21 + p)*8)*128 + t;
    float mx = -INFINITY, smv = 0.f;
#pragma unroll
    for (int k = 0; k < 8; ++k) { mx = fmaxf(mx, pm[base + k*128]); smv += ps[base + k*128]; }
    int chmax, chmean;
    if (p < P) { chmax = (dir ? 86 : 46) + p; chmean = (dir ? 106 : 66) + p; }
    else       { chmax = dir*2;              chmean = dir*2 + 1; }
    float* o = out + (size_t)rc*B*L*CH + (size_t)(b*L + t)*CH;
    o[chmax] = mx; o[chmean] = smv * (1.f/L);
    if (p == P) { (rc ? colsum : rowsum)[(dir*B + b)*L + t] = smv; }
}

// ---------------- attention vectors (mean & max) ----------------
// side0 -> att_*_h (reduce over j, out per i, reads cosT coalesced);
// side1 -> att_*_p (reduce over i, out per j, reads cosbuf).
#define PADW 52
__global__ __launch_bounds__(256) void att_kernel(
    const float* __restrict__ ctx_p, const float* __restrict__ ctx_h,
    const float* __restrict__ cosbuf, const float* __restrict__ cosT,
    const float* __restrict__ rowsum, const float* __restrict__ colsum,
    float* __restrict__ attbuf)
{
    const int b = blockIdx.x;
    const int dir = blockIdx.y >> 1, side = blockIdx.y & 1;
    const int rc = blockIdx.z >> 1, hh = blockIdx.z & 1;
    const int r0 = rc * 32;
    const int off = (dir ? H : 0) + hh*50;
    const int t = threadIdx.x;

    __shared__ float sv[L][PADW];
    __shared__ float cvT[L][36];

    const float* mat = (side ? cosbuf : cosT) + (size_t)(dir*B + b)*16384;
    const float* src = side ? ctx_p : ctx_h;

    for (int e = t; e < 26*L; e += 256) {
        int s = e / 26, g = e - s*26;
        float2 v;
        if (g < 25) v = *(const float2*)(src + (size_t)(b*L + s)*(2*H) + off + 2*g);
        else { v.x = 0.f; v.y = 0.f; }
        *(float2*)&sv[s][2*g] = v;
    }
    for (int e = t; e < 32*L; e += 256) {
        int r = e & 31, s = e >> 5;
        cvT[s][r] = mat[s*L + r0 + r];   // coalesced for both sides now
    }
    __syncthreads();

    const int tr = t & 15, th = t >> 4;
    if (th < 13) {
        float acc[2][4], amx[2][4];
#pragma unroll
        for (int rr = 0; rr < 2; ++rr)
#pragma unroll
            for (int q = 0; q < 4; ++q) { acc[rr][q] = 0.f; amx[rr][q] = -INFINITY; }
        for (int s = 0; s < L; ++s) {
            float2 c2 = *(const float2*)&cvT[s][2*tr];
            float4 v4 = *(const float4*)&sv[s][4*th];
            float cs[2] = {c2.x, c2.y};
            float vs[4] = {v4.x, v4.y, v4.z, v4.w};
#pragma unroll
            for (int rr = 0; rr < 2; ++rr)
#pragma unroll
                for (int q = 0; q < 4; ++q) {
                    float pr = cs[rr] * vs[q];
                    acc[rr][q] += pr;
                    amx[rr][q] = fmaxf(amx[rr][q], pr);
                }
        }
        const float* den = side ? colsum : rowsum;
#pragma unroll
        for (int rr = 0; rr < 2; ++rr) {
            int rg = r0 + 2*tr + rr;
            float d = fmaxf(den[(dir*B + b)*L + rg], EPSF);
            float* meanp = attbuf + ((((size_t)side*2 + 0)*2 + dir)*B*L + (b*L + rg))*H + hh*50;
            float* maxp  = attbuf + ((((size_t)side*2 + 1)*2 + dir)*B*L + (b*L + rg))*H + hh*50;
#pragma unroll
            for (int q = 0; q < 4; ++q) {
                int hl = 4*th + q;
                if (hl < 50) { meanp[hl] = acc[rr][q] / d; maxp[hl] = amx[rr][q]; }
            }
        }
    }
}

// ---------------- pointwise mpm: chunked, no per-thread arrays (no spill) ----------------
// grid (B, side, z=m*2+ihalf), block 64: thread = row i. acc[21]x3 via w^2 s_loads.
__global__ __launch_bounds__(64) void point_kernel(
    const float* __restrict__ ctx_p, const float* __restrict__ ctx_h,
    const float* __restrict__ w2t,
    const float* __restrict__ lastv, const float* __restrict__ attbuf,
    float* __restrict__ out)
{
    const int b = blockIdx.x, side = blockIdx.y;
    const int m = blockIdx.z >> 1, ih = blockIdx.z & 1;
    const int i = ih*64 + threadIdx.x;
    const int dir = m & 1;
    const int wsel_[6] = {0, 1, 4, 5, 6, 7};
    const int chb_[6]  = {4, 25, 126, 147, 168, 189};

    const float* v1p = (side ? ctx_h : ctx_p) + (size_t)(b*L + i)*(2*H) + dir*H;
    const float* v2p;
    if (m < 2) {
        v2p = lastv + ((size_t)((side ? 0 : 2) + dir)*B + b)*H;
    } else {
        int kind = (m >= 4) ? 1 : 0;
        v2p = attbuf + ((((size_t)side*2 + kind)*2 + dir)*B*L + (b*L + i))*H;
    }
    const float* wt = w2t + (size_t)wsel_[m]*2100;

    float s11[21], s22[21], s12[21];
#pragma unroll
    for (int p = 0; p < 21; ++p) { s11[p] = 0.f; s22[p] = 0.f; s12[p] = 0.f; }
    for (int g = 0; g < 25; ++g) {
        float4 x = *(const float4*)(v1p + 4*g);
        float4 y = *(const float4*)(v2p + 4*g);
        float xx[4] = {x.x*x.x, x.y*x.y, x.z*x.z, x.w*x.w};
        float yy[4] = {y.x*y.x, y.y*y.y, y.z*y.z, y.w*y.w};
        float xy[4] = {x.x*y.x, x.y*y.y, x.z*y.z, x.w*y.w};
        const float* wg = wt + g*84;   // uniform -> s_load
#pragma unroll
        for (int hh = 0; hh < 4; ++hh)
#pragma unroll
            for (int p = 0; p < 21; ++p) {
                float w2 = wg[hh*21 + p];
                s11[p] = fmaf(w2, xx[hh], s11[p]);
                s22[p] = fmaf(w2, yy[hh], s22[p]);
                s12[p] = fmaf(w2, xy[hh], s12[p]);
            }
    }
    float* orow = out + (size_t)side*B*L*CH + (size_t)(b*L + i)*CH;
#pragma unroll
    for (int p = 0; p < 21; ++p) {
        float c = s12[p] / (fmaxf(sqrtf(s11[p]), EPSF) * fmaxf(sqrtf(s22[p]), EPSF));
        orow[(p == P) ? chb_[m] : (chb_[m] + 1 + p)] = c;
    }
}

extern "C" void kernel_launch(void* const* d_in, const int* in_sizes, int n_in,
                              void* d_out, int out_size, void* d_ws, size_t ws_size,
                              hipStream_t stream) {
    const float* ctx_p  = (const float*)d_in[0];
    const int*   mask_p = (const int*)d_in[1];
    const float* ctx_h  = (const float*)d_in[2];
    const int*   mask_h = (const int*)d_in[3];
    const float* params = (const float*)d_in[4];
    float* out = (float*)d_out;

    float* ws = (float*)d_ws;
    float* cosbuf = ws + OFF_COS;
    float* cosT   = ws + OFF_COST;
    float* rowsum = ws + OFF_ROWSUM;
    float* colsum = ws + OFF_COLSUM;
    float* lastv  = ws + OFF_LASTV;
    float* w2t    = ws + OFF_W2T;
    float* nbuf   = ws + OFF_NBUF;
    float* rpmax  = ws + OFF_RPMAX;
    float* rpsum  = ws + OFF_RPSUM;
    float* cpmax  = ws + OFF_CPMAX;
    float* cpsum  = ws + OFF_CPSUM;
    float* attbuf = ws + OFF_ATT;

    prep_kernel  <<<dim3(B, 2),      128, 0, stream>>>(ctx_p, mask_p, ctx_h, mask_h, lastv);
    wprep_kernel <<<dim3(66),        256, 0, stream>>>(params, w2t);
    norm_kernel  <<<dim3(B, 2, 2),   128, 0, stream>>>(ctx_p, ctx_h, w2t, nbuf);
    pair_kernel  <<<dim3(B, 2, 64),  256, 0, stream>>>(ctx_p, ctx_h, w2t, nbuf,
                                                       cosbuf, cosT, rpmax, rpsum, cpmax, cpsum);
    reduce_kernel<<<dim3(32, 21, 2), 128, 0, stream>>>(rpmax, rpsum, cpmax, cpsum,
                                                       out, rowsum, colsum);
    att_kernel   <<<dim3(B, 4, 8),   256, 0, stream>>>(ctx_p, ctx_h, cosbuf, cosT,
                                                       rowsum, colsum, attbuf);
    point_kernel <<<dim3(B, 2, 12),  64, 0, stream>>>(ctx_p, ctx_h, w2t, lastv, attbuf, out);
}

// Round 3
// 148.758 us; speedup vs baseline: 1.5753x; 1.2069x over previous
//
#include <hip/hip_runtime.h>
#include <math.h>

#define B 16
#define L 128
#define H 100
#define P 20
#define CH 210
#define EPSF 1e-8f

// workspace layout (float offsets), total ~11.6 MB
#define OFF_COS    0u         // [dir][b][i][j]            524288
#define OFF_COST   524288u    // [dir][b][j][i]            524288
#define OFF_ROWSUM 1048576u   // [dir][b][i]               4096
#define OFF_COLSUM 1052672u   // [dir][b][j]               4096
#define OFF_LASTV  1056768u   // [is_h*2+dir][b][h]        6400
#define OFF_W2T    1063168u   // [m8][g25][hh4][p21] w^2   16800 (p==20 -> 1.0)
#define OFF_W2F    1079968u   // [m8][p21][h128] w^2 f32   21504 (h>=100 -> 0)
#define OFF_NBUF   1101472u   // [dir*2+side][b][p21][i]   172032
#define OFF_ATT    1273504u   // [(side*2+kind)*2+dir][b][r][h] 1638400

typedef __attribute__((ext_vector_type(8))) short bf16x8;
typedef __attribute__((ext_vector_type(4))) float f32x4;

__device__ inline unsigned short f2bf(float x) {   // RNE float->bf16 bits
    union { float f; unsigned u; } c; c.f = x;
    unsigned r = c.u + 0x7fffu + ((c.u >> 16) & 1u);
    return (unsigned short)(r >> 16);
}

// ---------------- prep: lengths -> last vectors ----------------
__global__ __launch_bounds__(128) void prep_kernel(
    const float* __restrict__ ctx_p, const int* __restrict__ mask_p,
    const float* __restrict__ ctx_h, const int* __restrict__ mask_h,
    float* __restrict__ lastv)
{
    const int b = blockIdx.x, is_h = blockIdx.y, t = threadIdx.x;
    const float* ctx = is_h ? ctx_h : ctx_p;
    const int* mask = is_h ? mask_h : mask_p;
    __shared__ int sm[L];
    sm[t] = mask[b*L + t];
    __syncthreads();
    for (int s = 64; s > 0; s >>= 1) {
        if (t < s) sm[t] += sm[t + s];
        __syncthreads();
    }
    int last = sm[0] - 1;
    if (last < 0) last = 0;
    if (t < H) {
        lastv[((size_t)(is_h*2 + 0)*B + b)*H + t] = ctx[(size_t)(b*L + last)*(2*H) + t];
        lastv[((size_t)(is_h*2 + 1)*B + b)*H + t] = ctx[(size_t)(b*L + 0)*(2*H) + H + t];
    }
}

// ---------------- w^2 tables ----------------
__global__ __launch_bounds__(256) void wprep_kernel(
    const float* __restrict__ params, float* __restrict__ w2t, float* __restrict__ w2f)
{
    int e = blockIdx.x*256 + threadIdx.x;
    if (e < 8*25*4*21) {
        int m = e / 2100, r = e % 2100;
        int g = r / 84, q = r % 84, hh = q / 21, p = q % 21;
        int h = 4*g + hh;
        float v = 1.f;
        if (p < P) { float w = params[((size_t)m*P + p)*H + h]; v = w*w; }
        w2t[e] = v;
    }
    int e2 = e - 16800;
    if (e2 >= 0 && e2 < 8*21*128) {
        int m = e2 / (21*128), r = e2 % (21*128), p = r / 128, h = r % 128;
        float v = 0.f;
        if (h < H) {
            if (p < P) { float w = params[((size_t)m*P + p)*H + h]; v = w*w; }
            else v = 1.f;
        }
        w2f[e2] = v;
    }
}

// ---------------- weighted row norms (fp32-exact): nbuf[dir*2+side][b][p][i] ----------------
__global__ __launch_bounds__(128) void norm_kernel(
    const float* __restrict__ ctx_p, const float* __restrict__ ctx_h,
    const float* __restrict__ w2t, float* __restrict__ nbuf)
{
    const int b = blockIdx.x, dir = blockIdx.y, side = blockIdx.z;
    const int i = threadIdx.x;
    const float* row = (side ? ctx_h : ctx_p) + (size_t)(b*L + i)*(2*H) + dir*H;
    const float* wt = w2t + (size_t)(2 + dir)*2100;
    float n2[21];
#pragma unroll
    for (int p = 0; p < 21; ++p) n2[p] = 0.f;
    for (int g = 0; g < 25; ++g) {
        float4 v = *(const float4*)(row + 4*g);
        float sq[4] = {v.x*v.x, v.y*v.y, v.z*v.z, v.w*v.w};
        const float* wg = wt + g*84;
#pragma unroll
        for (int hh = 0; hh < 4; ++hh)
#pragma unroll
            for (int p = 0; p < 21; ++p)
                n2[p] = fmaf(wg[hh*21 + p], sq[hh], n2[p]);
    }
    float* nb = nbuf + ((size_t)((dir*2 + side)*B + b)*21)*128;
#pragma unroll
    for (int p = 0; p < 21; ++p) nb[p*128 + i] = sqrtf(n2[p]);
}

// ---------------- pairwise via MFMA: one (b,dir,p) per block ----------------
__global__ __launch_bounds__(256, 2) void pair_kernel(
    const float* __restrict__ ctx_p, const float* __restrict__ ctx_h,
    const float* __restrict__ w2f, const float* __restrict__ nbuf,
    float* __restrict__ cosbuf, float* __restrict__ cosT,
    float* __restrict__ rowsum, float* __restrict__ colsum,
    float* __restrict__ out)
{
    const int b = blockIdx.x, dir = blockIdx.y, p = blockIdx.z;
    const int t = threadIdx.x;
    __shared__ short sB[2048*8];            // 32KB: frag (cg*4+kt)*64+lane, 8 bf16
    __shared__ float colred[2][4][128];     // [kind][wave][col]

    // stage B (ctx_h dir-half) into MFMA frag layout; zero-pad k>=100
    for (int e = t; e < 2048; e += 256) {
        int cg = e >> 8, kt = (e >> 6) & 3, qq = (e >> 4) & 3, rl2 = e & 15;
        int row = cg*16 + rl2, kb = kt*32 + qq*8;
        float v[8];
#pragma unroll
        for (int j = 0; j < 8; ++j) v[j] = 0.f;
        const float* src = ctx_h + (size_t)(b*L + row)*(2*H) + dir*H;
        if (kb < H)     { float4 f = *(const float4*)(src + kb);     v[0]=f.x; v[1]=f.y; v[2]=f.z; v[3]=f.w; }
        if (kb + 4 < H) { float4 f = *(const float4*)(src + kb + 4); v[4]=f.x; v[5]=f.y; v[6]=f.z; v[7]=f.w; }
        bf16x8 pk;
#pragma unroll
        for (int j = 0; j < 8; ++j) pk[j] = (short)f2bf(v[j]);
        *(bf16x8*)&sB[e*8] = pk;
    }

    // A frags: global->reg direct, scaled by w^2_p (each element read once)
    const int w = t >> 6, lane = t & 63, q = lane >> 4, rl = lane & 15;
    const float* w2row = w2f + ((size_t)(2 + dir)*21 + p)*128;
    bf16x8 af[2][4];
#pragma unroll
    for (int rgi = 0; rgi < 2; ++rgi) {
        int row = (w*2 + rgi)*16 + rl;
        const float* src = ctx_p + (size_t)(b*L + row)*(2*H) + dir*H;
#pragma unroll
        for (int kt = 0; kt < 4; ++kt) {
            int kb = kt*32 + q*8;
            float v[8];
#pragma unroll
            for (int j = 0; j < 8; ++j) v[j] = 0.f;
            if (kb < H) {
                float4 f = *(const float4*)(src + kb);
                float4 wv = *(const float4*)(w2row + kb);
                v[0]=f.x*wv.x; v[1]=f.y*wv.y; v[2]=f.z*wv.z; v[3]=f.w*wv.w;
            }
            if (kb + 4 < H) {
                float4 f = *(const float4*)(src + kb + 4);
                float4 wv = *(const float4*)(w2row + kb + 4);
                v[4]=f.x*wv.x; v[5]=f.y*wv.y; v[6]=f.z*wv.z; v[7]=f.w*wv.w;
            }
            bf16x8 pk;
#pragma unroll
            for (int j = 0; j < 8; ++j) pk[j] = (short)f2bf(v[j]);
            af[rgi][kt] = pk;
        }
    }
    __syncthreads();

    f32x4 acc[2][8];
#pragma unroll
    for (int rgi = 0; rgi < 2; ++rgi)
#pragma unroll
        for (int cg = 0; cg < 8; ++cg) acc[rgi][cg] = (f32x4)0.f;
#pragma unroll
    for (int kt = 0; kt < 4; ++kt) {
#pragma unroll
        for (int cg = 0; cg < 8; ++cg) {
            bf16x8 bfr = *(bf16x8*)&sB[((cg*4 + kt)*64 + lane)*8];
            acc[0][cg] = __builtin_amdgcn_mfma_f32_16x16x32_bf16(af[0][kt], bfr, acc[0][cg], 0, 0, 0);
            acc[1][cg] = __builtin_amdgcn_mfma_f32_16x16x32_bf16(af[1][kt], bfr, acc[1][cg], 0, 0, 0);
        }
    }

    const float* nbA = nbuf + (((size_t)(dir*2 + 0)*B + b)*21 + p)*128;
    const float* nbB = nbuf + (((size_t)(dir*2 + 1)*B + b)*21 + p)*128;
    float na[2][4];
#pragma unroll
    for (int rgi = 0; rgi < 2; ++rgi)
#pragma unroll
        for (int r = 0; r < 4; ++r) na[rgi][r] = nbA[(w*2 + rgi)*16 + q*4 + r];
    float nbv[8];
#pragma unroll
    for (int cg = 0; cg < 8; ++cg) nbv[cg] = nbB[cg*16 + rl];

    const bool iscos = (p == P);
    float* cosm  = cosbuf + (size_t)(dir*B + b)*16384;
    float* cosmT = cosT   + (size_t)(dir*B + b)*16384;

    int chmax, chmean;
    if (p < P) { chmax = (dir ? 86 : 46) + p; chmean = (dir ? 106 : 66) + p; }
    else       { chmax = dir*2;              chmean = dir*2 + 1; }

    float rowm[2][4], rows_[2][4], colm[8], cols_[8];
#pragma unroll
    for (int rgi = 0; rgi < 2; ++rgi)
#pragma unroll
        for (int r = 0; r < 4; ++r) { rowm[rgi][r] = -INFINITY; rows_[rgi][r] = 0.f; }
#pragma unroll
    for (int cg = 0; cg < 8; ++cg) { colm[cg] = -INFINITY; cols_[cg] = 0.f; }

#pragma unroll
    for (int rgi = 0; rgi < 2; ++rgi) {
        int i0 = (w*2 + rgi)*16 + q*4;
#pragma unroll
        for (int cg = 0; cg < 8; ++cg) {
            float m[4];
#pragma unroll
            for (int r = 0; r < 4; ++r) {
                float d = fmaxf(na[rgi][r]*nbv[cg], EPSF);
                m[r] = acc[rgi][cg][r] * __builtin_amdgcn_rcpf(d);
                rowm[rgi][r] = fmaxf(rowm[rgi][r], m[r]);
                rows_[rgi][r] += m[r];
            }
            float cM = fmaxf(fmaxf(m[0], m[1]), fmaxf(m[2], m[3]));
            colm[cg] = fmaxf(colm[cg], cM);
            cols_[cg] += (m[0] + m[1]) + (m[2] + m[3]);
            if (iscos) {
                int j = cg*16 + rl;
                float4 f4; f4.x = m[0]; f4.y = m[1]; f4.z = m[2]; f4.w = m[3];
                *(float4*)&cosmT[j*128 + i0] = f4;
#pragma unroll
                for (int r = 0; r < 4; ++r) cosm[(i0 + r)*128 + j] = m[r];
            }
        }
    }
#pragma unroll
    for (int rgi = 0; rgi < 2; ++rgi)
#pragma unroll
        for (int r = 0; r < 4; ++r) {
            float mx = rowm[rgi][r], sm = rows_[rgi][r];
#pragma unroll
            for (int d = 1; d < 16; d <<= 1) {
                mx = fmaxf(mx, __shfl_xor(mx, d));
                sm += __shfl_xor(sm, d);
            }
            if (rl == 0) {
                int i = (w*2 + rgi)*16 + q*4 + r;
                float* orow = out + (size_t)(b*L + i)*CH;
                orow[chmax] = mx; orow[chmean] = sm * (1.f/L);
                if (iscos) rowsum[(dir*B + b)*L + i] = sm;
            }
        }
#pragma unroll
    for (int cg = 0; cg < 8; ++cg) {
        float mx = colm[cg], sm = cols_[cg];
        mx = fmaxf(mx, __shfl_xor(mx, 16)); sm += __shfl_xor(sm, 16);
        mx = fmaxf(mx, __shfl_xor(mx, 32)); sm += __shfl_xor(sm, 32);
        if (q == 0) { colred[0][w][cg*16 + rl] = mx; colred[1][w][cg*16 + rl] = sm; }
    }
    __syncthreads();
    {
        int c = t & 127, kind = t >> 7;
        float v0 = colred[kind][0][c], v1 = colred[kind][1][c];
        float v2 = colred[kind][2][c], v3 = colred[kind][3][c];
        float* oh = out + (size_t)B*L*CH + (size_t)(b*L + c)*CH;
        if (kind == 0) {
            oh[chmax] = fmaxf(fmaxf(v0, v1), fmaxf(v2, v3));
        } else {
            float sm = (v0 + v1) + (v2 + v3);
            oh[chmean] = sm * (1.f/L);
            if (iscos) colsum[(dir*B + b)*L + c] = sm;
        }
    }
}

// ---------------- attention vectors (mean & max) ----------------
__global__ __launch_bounds__(256) void att_kernel(
    const float* __restrict__ ctx_p, const float* __restrict__ ctx_h,
    const float* __restrict__ cosbuf, const float* __restrict__ cosT,
    const float* __restrict__ rowsum, const float* __restrict__ colsum,
    float* __restrict__ attbuf)
{
    const int b = blockIdx.x;
    const int dir = blockIdx.y >> 1, side = blockIdx.y & 1;
    const int rc = blockIdx.z, r0 = rc*16;
    const int t = threadIdx.x;

    __shared__ float sv[L][H];     // 51.2KB
    __shared__ float cvT[L][16];   // 8KB

    const float* mat = (side ? cosbuf : cosT) + (size_t)(dir*B + b)*16384;
    const float* src = side ? ctx_p : ctx_h;

    for (int e = t; e < 3200; e += 256) {
        int row = e / 25, g = e - row*25;
        *(float4*)&sv[row][4*g] =
            *(const float4*)(src + (size_t)(b*L + row)*(2*H) + dir*H + 4*g);
    }
    for (int e = t; e < 2048; e += 256) {
        int s = e >> 4, r = e & 15;
        cvT[s][r] = mat[s*L + r0 + r];
    }
    __syncthreads();

    const int tr = t & 7, th = t >> 3;   // 2 rows x 4 h per thread, th<25 active
    if (th < 25) {
        float acc[2][4], amx[2][4];
#pragma unroll
        for (int rr = 0; rr < 2; ++rr)
#pragma unroll
            for (int qq = 0; qq < 4; ++qq) { acc[rr][qq] = 0.f; amx[rr][qq] = -INFINITY; }
        for (int s = 0; s < L; ++s) {
            float2 c2 = *(const float2*)&cvT[s][2*tr];
            float4 v4 = *(const float4*)&sv[s][4*th];
            float cs[2] = {c2.x, c2.y};
            float vs[4] = {v4.x, v4.y, v4.z, v4.w};
#pragma unroll
            for (int rr = 0; rr < 2; ++rr)
#pragma unroll
                for (int qq = 0; qq < 4; ++qq) {
                    float pr = cs[rr] * vs[qq];
                    acc[rr][qq] += pr;
                    amx[rr][qq] = fmaxf(amx[rr][qq], pr);
                }
        }
        const float* den = side ? colsum : rowsum;
#pragma unroll
        for (int rr = 0; rr < 2; ++rr) {
            int rg = r0 + 2*tr + rr;
            float d = fmaxf(den[(dir*B + b)*L + rg], EPSF);
            float* meanp = attbuf + ((((size_t)side*2 + 0)*2 + dir)*B*L + (b*L + rg))*H + 4*th;
            float* maxp  = attbuf + ((((size_t)side*2 + 1)*2 + dir)*B*L + (b*L + rg))*H + 4*th;
            float4 fm; fm.x = acc[rr][0]/d; fm.y = acc[rr][1]/d; fm.z = acc[rr][2]/d; fm.w = acc[rr][3]/d;
            float4 fx; fx.x = amx[rr][0]; fx.y = amx[rr][1]; fx.z = amx[rr][2]; fx.w = amx[rr][3];
            *(float4*)meanp = fm;
            *(float4*)maxp  = fx;
        }
    }
}

// ---------------- pointwise mpm: h split across 2 waves, LDS combine ----------------
__global__ __launch_bounds__(128) void point_kernel(
    const float* __restrict__ ctx_p, const float* __restrict__ ctx_h,
    const float* __restrict__ w2t,
    const float* __restrict__ lastv, const float* __restrict__ attbuf,
    float* __restrict__ out)
{
    const int b = blockIdx.x, side = blockIdx.y;
    const int m = blockIdx.z >> 1, ih = blockIdx.z & 1;
    const int t = threadIdx.x;
    const int il = t & 63, half = t >> 6;
    const int i = ih*64 + il;
    const int dir = m & 1;
    const int wsel_[6] = {0, 1, 4, 5, 6, 7};
    const int chb_[6]  = {4, 25, 126, 147, 168, 189};

    const float* v1p = (side ? ctx_h : ctx_p) + (size_t)(b*L + i)*(2*H) + dir*H;
    const float* v2p;
    if (m < 2) {
        v2p = lastv + ((size_t)((side ? 0 : 2) + dir)*B + b)*H;
    } else {
        int kind = (m >= 4) ? 1 : 0;
        v2p = attbuf + ((((size_t)side*2 + kind)*2 + dir)*B*L + (b*L + i))*H;
    }
    const float* wt = w2t + (size_t)wsel_[m]*2100;

    float s11[21], s22[21], s12[21];
#pragma unroll
    for (int p = 0; p < 21; ++p) { s11[p] = 0.f; s22[p] = 0.f; s12[p] = 0.f; }
    const int g0 = half ? 13 : 0, g1 = half ? 25 : 13;
    for (int g = g0; g < g1; ++g) {
        float4 x = *(const float4*)(v1p + 4*g);
        float4 y = *(const float4*)(v2p + 4*g);
        float xx[4] = {x.x*x.x, x.y*x.y, x.z*x.z, x.w*x.w};
        float yy[4] = {y.x*y.x, y.y*y.y, y.z*y.z, y.w*y.w};
        float xy[4] = {x.x*y.x, x.y*y.y, x.z*y.z, x.w*y.w};
        const float* wg = wt + g*84;
#pragma unroll
        for (int hh = 0; hh < 4; ++hh)
#pragma unroll
            for (int p = 0; p < 21; ++p) {
                float w2 = wg[hh*21 + p];
                s11[p] = fmaf(w2, xx[hh], s11[p]);
                s22[p] = fmaf(w2, yy[hh], s22[p]);
                s12[p] = fmaf(w2, xy[hh], s12[p]);
            }
    }
    __shared__ float red[3][21][64];
    if (half) {
#pragma unroll
        for (int p = 0; p < 21; ++p) {
            red[0][p][il] = s11[p]; red[1][p][il] = s22[p]; red[2][p][il] = s12[p];
        }
    }
    __syncthreads();
    if (!half) {
        float* orow = out + (size_t)side*B*L*CH + (size_t)(b*L + i)*CH;
#pragma unroll
        for (int p = 0; p < 21; ++p) {
            float a = s11[p] + red[0][p][il];
            float c = s22[p] + red[1][p][il];
            float d = s12[p] + red[2][p][il];
            float cv = d / (fmaxf(sqrtf(a), EPSF) * fmaxf(sqrtf(c), EPSF));
            orow[(p == P) ? chb_[m] : (chb_[m] + 1 + p)] = cv;
        }
    }
}

extern "C" void kernel_launch(void* const* d_in, const int* in_sizes, int n_in,
                              void* d_out, int out_size, void* d_ws, size_t ws_size,
                              hipStream_t stream) {
    const float* ctx_p  = (const float*)d_in[0];
    const int*   mask_p = (const int*)d_in[1];
    const float* ctx_h  = (const float*)d_in[2];
    const int*   mask_h = (const int*)d_in[3];
    const float* params = (const float*)d_in[4];
    float* out = (float*)d_out;

    float* ws = (float*)d_ws;
    float* cosbuf = ws + OFF_COS;
    float* cosT   = ws + OFF_COST;
    float* rowsum = ws + OFF_ROWSUM;
    float* colsum = ws + OFF_COLSUM;
    float* lastv  = ws + OFF_LASTV;
    float* w2t    = ws + OFF_W2T;
    float* w2f    = ws + OFF_W2F;
    float* nbuf   = ws + OFF_NBUF;
    float* attbuf = ws + OFF_ATT;

    prep_kernel <<<dim3(B, 2),     128, 0, stream>>>(ctx_p, mask_p, ctx_h, mask_h, lastv);
    wprep_kernel<<<dim3(150),      256, 0, stream>>>(params, w2t, w2f);
    norm_kernel <<<dim3(B, 2, 2),  128, 0, stream>>>(ctx_p, ctx_h, w2t, nbuf);
    pair_kernel <<<dim3(B, 2, 21), 256, 0, stream>>>(ctx_p, ctx_h, w2f, nbuf,
                                                     cosbuf, cosT, rowsum, colsum, out);
    att_kernel  <<<dim3(B, 4, 8),  256, 0, stream>>>(ctx_p, ctx_h, cosbuf, cosT,
                                                     rowsum, colsum, attbuf);
    point_kernel<<<dim3(B, 2, 12), 128, 0, stream>>>(ctx_p, ctx_h, w2t, lastv, attbuf, out);
}

// Round 5
// 135.064 us; speedup vs baseline: 1.7350x; 1.1014x over previous
//
#include <hip/hip_runtime.h>
#include <math.h>

#define B 16
#define L 128
#define H 100
#define P 20
#define CH 210
#define EPSF 1e-8f

// workspace layout (float offsets), total ~10.9 MB
#define OFF_COS    0u         // [dir][b][i][j]            524288
#define OFF_COST   524288u    // [dir][b][j][i]            524288
#define OFF_ROWSUM 1048576u   // [dir][b][i]               4096
#define OFF_COLSUM 1052672u   // [dir][b][j]               4096
#define OFF_LASTV  1056768u   // [is_h*2+dir][b][h]        6400
#define OFF_W2T    1063168u   // [m8][g25][hh4][p21] w^2   16800 (p==20 -> 1.0)
#define OFF_ATT    1079968u   // [(side*2+kind)*2+dir][b][r][h] 1638400

typedef __attribute__((ext_vector_type(8))) short bf16x8;
typedef __attribute__((ext_vector_type(4))) float f32x4;

__device__ inline unsigned short f2bf(float x) {   // RNE float->bf16 bits
    union { float f; unsigned u; } c; c.f = x;
    unsigned r = c.u + 0x7fffu + ((c.u >> 16) & 1u);
    return (unsigned short)(r >> 16);
}

// ================= dispatch 1: pair (672 tasks) + w2t (1 blk) + lastv (32 blks) ========
// LDS: sB 32768 + colred 4096 + nlds 1024 = 37888 B
__global__ __launch_bounds__(256, 2) void pair_kernel(
    const float* __restrict__ ctx_p, const float* __restrict__ ctx_h,
    const int* __restrict__ mask_p, const int* __restrict__ mask_h,
    const float* __restrict__ params,
    float* __restrict__ cosbuf, float* __restrict__ cosT,
    float* __restrict__ rowsum, float* __restrict__ colsum,
    float* __restrict__ lastv, float* __restrict__ w2t,
    float* __restrict__ out)
{
    __shared__ __align__(16) char smem[37888];
    const int k = blockIdx.x, t = threadIdx.x;

    if (k >= 672) {
        if (k == 672) {
            // w2t [m][g][hh][p]; p==20 -> 1.0  (consumed by point, 2 dispatches later)
            for (int e = t; e < 16800; e += 256) {
                int m = e / 2100, r = e % 2100;
                int g = r / 84, qq = r % 84, hh = qq / 21, p = qq % 21;
                int h = 4*g + hh;
                float v = 1.f;
                if (p < P) { float w = params[((size_t)m*P + p)*H + h]; v = w*w; }
                w2t[e] = v;
            }
        } else {
            // lastv task: b, is_h
            const int task = k - 673, b = task >> 1, is_h = task & 1;
            const float* ctx = is_h ? ctx_h : ctx_p;
            const int* mask = is_h ? mask_h : mask_p;
            int* sm = (int*)smem;
            if (t < 128) sm[t] = mask[b*L + t];
            __syncthreads();
            for (int s = 64; s > 0; s >>= 1) {
                if (t < s) sm[t] += sm[t + s];
                __syncthreads();
            }
            int last = sm[0] - 1;
            if (last < 0) last = 0;
            if (t < H) {
                lastv[((size_t)(is_h*2 + 0)*B + b)*H + t] = ctx[(size_t)(b*L + last)*(2*H) + t];
                lastv[((size_t)(is_h*2 + 1)*B + b)*H + t] = ctx[(size_t)(b*L + 0)*(2*H) + H + t];
            }
        }
        return;
    }

    // ---- pair task (b, dir, p) ----
    const int b = k & 15, dir = (k >> 4) & 1, p = k >> 5;
    short* sB     = (short*)smem;                 // frag (cg*4+kt)*64+lane, 8 bf16
    float* colred = (float*)(smem + 32768);       // [kind2][wave4][col128]
    float* nlds   = (float*)(smem + 32768 + 4096);// [side2][row128]

    // stage B (ctx_h dir-half) into MFMA frag layout; zero-pad k>=100
    for (int e = t; e < 2048; e += 256) {
        int cgi = e >> 8, kt = (e >> 6) & 3, qq = (e >> 4) & 3, rl2 = e & 15;
        int row = cgi*16 + rl2, kb = kt*32 + qq*8;
        float v[8];
#pragma unroll
        for (int j = 0; j < 8; ++j) v[j] = 0.f;
        const float* src = ctx_h + (size_t)(b*L + row)*(2*H) + dir*H;
        if (kb < H)     { float4 f = *(const float4*)(src + kb);     v[0]=f.x; v[1]=f.y; v[2]=f.z; v[3]=f.w; }
        if (kb + 4 < H) { float4 f = *(const float4*)(src + kb + 4); v[4]=f.x; v[5]=f.y; v[6]=f.z; v[7]=f.w; }
        bf16x8 pk;
#pragma unroll
        for (int j = 0; j < 8; ++j) pk[j] = (short)f2bf(v[j]);
        *(bf16x8*)&sB[e*8] = pk;
    }

    const float* prow = params + ((size_t)(2 + dir)*P + p)*H;   // valid only when p<20

    // A frags: global->reg direct, scaled by w^2_p (from params, squared in-reg)
    const int w = t >> 6, lane = t & 63, q = lane >> 4, rl = lane & 15;
    bf16x8 af[2][4];
#pragma unroll
    for (int rgi = 0; rgi < 2; ++rgi) {
        int row = (w*2 + rgi)*16 + rl;
        const float* src = ctx_p + (size_t)(b*L + row)*(2*H) + dir*H;
#pragma unroll
        for (int kt = 0; kt < 4; ++kt) {
            int kb = kt*32 + q*8;
            float v[8];
#pragma unroll
            for (int j = 0; j < 8; ++j) v[j] = 0.f;
            if (p < P) {
                if (kb < H) {
                    float4 f = *(const float4*)(src + kb);
                    float4 wv = *(const float4*)(prow + kb);
                    v[0]=f.x*wv.x*wv.x; v[1]=f.y*wv.y*wv.y; v[2]=f.z*wv.z*wv.z; v[3]=f.w*wv.w*wv.w;
                }
                if (kb + 4 < H) {
                    float4 f = *(const float4*)(src + kb + 4);
                    float4 wv = *(const float4*)(prow + kb + 4);
                    v[4]=f.x*wv.x*wv.x; v[5]=f.y*wv.y*wv.y; v[6]=f.z*wv.z*wv.z; v[7]=f.w*wv.w*wv.w;
                }
            } else {
                if (kb < H)     { float4 f = *(const float4*)(src + kb);     v[0]=f.x; v[1]=f.y; v[2]=f.z; v[3]=f.w; }
                if (kb + 4 < H) { float4 f = *(const float4*)(src + kb + 4); v[4]=f.x; v[5]=f.y; v[6]=f.z; v[7]=f.w; }
            }
            bf16x8 pk;
#pragma unroll
            for (int j = 0; j < 8; ++j) pk[j] = (short)f2bf(v[j]);
            af[rgi][kt] = pk;
        }
    }

    // in-block weighted norms (fp32-exact): thread t -> row t&127 of side t>>7
    {
        const int r = t & 127, sd = t >> 7;
        const float* nrow = (sd ? ctx_h : ctx_p) + (size_t)(b*L + r)*(2*H) + dir*H;
        float n2 = 0.f;
        if (p < P) {
            for (int g = 0; g < 25; ++g) {
                float4 v = *(const float4*)(nrow + 4*g);
                float4 wv = *(const float4*)(prow + 4*g);
                n2 = fmaf(wv.x*wv.x, v.x*v.x, n2);
                n2 = fmaf(wv.y*wv.y, v.y*v.y, n2);
                n2 = fmaf(wv.z*wv.z, v.z*v.z, n2);
                n2 = fmaf(wv.w*wv.w, v.w*v.w, n2);
            }
        } else {
            for (int g = 0; g < 25; ++g) {
                float4 v = *(const float4*)(nrow + 4*g);
                n2 = fmaf(v.x, v.x, n2); n2 = fmaf(v.y, v.y, n2);
                n2 = fmaf(v.z, v.z, n2); n2 = fmaf(v.w, v.w, n2);
            }
        }
        nlds[sd*128 + r] = sqrtf(n2);
    }
    __syncthreads();

    f32x4 acc[2][8];
#pragma unroll
    for (int rgi = 0; rgi < 2; ++rgi)
#pragma unroll
        for (int cgi = 0; cgi < 8; ++cgi) acc[rgi][cgi] = (f32x4)0.f;
#pragma unroll
    for (int kt = 0; kt < 4; ++kt) {
#pragma unroll
        for (int cgi = 0; cgi < 8; ++cgi) {
            bf16x8 bfr = *(bf16x8*)&sB[((cgi*4 + kt)*64 + lane)*8];
            acc[0][cgi] = __builtin_amdgcn_mfma_f32_16x16x32_bf16(af[0][kt], bfr, acc[0][cgi], 0, 0, 0);
            acc[1][cgi] = __builtin_amdgcn_mfma_f32_16x16x32_bf16(af[1][kt], bfr, acc[1][cgi], 0, 0, 0);
        }
    }

    float na[2][4];
#pragma unroll
    for (int rgi = 0; rgi < 2; ++rgi)
#pragma unroll
        for (int r = 0; r < 4; ++r) na[rgi][r] = nlds[0*128 + (w*2 + rgi)*16 + q*4 + r];
    float nbv[8];
#pragma unroll
    for (int cgi = 0; cgi < 8; ++cgi) nbv[cgi] = nlds[1*128 + cgi*16 + rl];

    const bool iscos = (p == P);
    float* cosm  = cosbuf + (size_t)(dir*B + b)*16384;
    float* cosmT = cosT   + (size_t)(dir*B + b)*16384;

    int chmax, chmean;
    if (p < P) { chmax = (dir ? 86 : 46) + p; chmean = (dir ? 106 : 66) + p; }
    else       { chmax = dir*2;              chmean = dir*2 + 1; }

    float rowm[2][4], rows_[2][4], colm[8], cols_[8];
#pragma unroll
    for (int rgi = 0; rgi < 2; ++rgi)
#pragma unroll
        for (int r = 0; r < 4; ++r) { rowm[rgi][r] = -INFINITY; rows_[rgi][r] = 0.f; }
#pragma unroll
    for (int cgi = 0; cgi < 8; ++cgi) { colm[cgi] = -INFINITY; cols_[cgi] = 0.f; }

#pragma unroll
    for (int rgi = 0; rgi < 2; ++rgi) {
        int i0 = (w*2 + rgi)*16 + q*4;
#pragma unroll
        for (int cgi = 0; cgi < 8; ++cgi) {
            float m[4];
#pragma unroll
            for (int r = 0; r < 4; ++r) {
                float d = fmaxf(na[rgi][r]*nbv[cgi], EPSF);
                m[r] = acc[rgi][cgi][r] * __builtin_amdgcn_rcpf(d);
                rowm[rgi][r] = fmaxf(rowm[rgi][r], m[r]);
                rows_[rgi][r] += m[r];
            }
            float cM = fmaxf(fmaxf(m[0], m[1]), fmaxf(m[2], m[3]));
            colm[cgi] = fmaxf(colm[cgi], cM);
            cols_[cgi] += (m[0] + m[1]) + (m[2] + m[3]);
            if (iscos) {
                int j = cgi*16 + rl;
                float4 f4; f4.x = m[0]; f4.y = m[1]; f4.z = m[2]; f4.w = m[3];
                *(float4*)&cosmT[j*128 + i0] = f4;
#pragma unroll
                for (int r = 0; r < 4; ++r) cosm[(i0 + r)*128 + j] = m[r];
            }
        }
    }
#pragma unroll
    for (int rgi = 0; rgi < 2; ++rgi)
#pragma unroll
        for (int r = 0; r < 4; ++r) {
            float mx = rowm[rgi][r], sm = rows_[rgi][r];
#pragma unroll
            for (int d = 1; d < 16; d <<= 1) {
                mx = fmaxf(mx, __shfl_xor(mx, d));
                sm += __shfl_xor(sm, d);
            }
            if (rl == 0) {
                int i = (w*2 + rgi)*16 + q*4 + r;
                float* orow = out + (size_t)(b*L + i)*CH;
                orow[chmax] = mx; orow[chmean] = sm * (1.f/L);
                if (iscos) rowsum[(dir*B + b)*L + i] = sm;
            }
        }
#pragma unroll
    for (int cgi = 0; cgi < 8; ++cgi) {
        float mx = colm[cgi], sm = cols_[cgi];
        mx = fmaxf(mx, __shfl_xor(mx, 16)); sm += __shfl_xor(sm, 16);
        mx = fmaxf(mx, __shfl_xor(mx, 32)); sm += __shfl_xor(sm, 32);
        if (q == 0) {
            colred[(0*4 + w)*128 + cgi*16 + rl] = mx;
            colred[(1*4 + w)*128 + cgi*16 + rl] = sm;
        }
    }
    __syncthreads();
    {
        int c = t & 127, kind = t >> 7;
        float v0 = colred[(kind*4 + 0)*128 + c], v1 = colred[(kind*4 + 1)*128 + c];
        float v2 = colred[(kind*4 + 2)*128 + c], v3 = colred[(kind*4 + 3)*128 + c];
        float* oh = out + (size_t)B*L*CH + (size_t)(b*L + c)*CH;
        if (kind == 0) {
            oh[chmax] = fmaxf(fmaxf(v0, v1), fmaxf(v2, v3));
        } else {
            float sm = (v0 + v1) + (v2 + v3);
            oh[chmean] = sm * (1.f/L);
            if (iscos) colsum[(dir*B + b)*L + c] = sm;
        }
    }
}

// ================= dispatch 2: attention vectors (mean & max) =================
__global__ __launch_bounds__(256) void att_kernel(
    const float* __restrict__ ctx_p, const float* __restrict__ ctx_h,
    const float* __restrict__ cosbuf, const float* __restrict__ cosT,
    const float* __restrict__ rowsum, const float* __restrict__ colsum,
    float* __restrict__ attbuf)
{
    const int b = blockIdx.x;
    const int dir = blockIdx.y >> 1, side = blockIdx.y & 1;
    const int rc = blockIdx.z, r0 = rc*16;
    const int t = threadIdx.x;

    __shared__ float sv[L][H];     // 51.2KB
    __shared__ float cvT[L][16];   // 8KB

    const float* mat = (side ? cosbuf : cosT) + (size_t)(dir*B + b)*16384;
    const float* src = side ? ctx_p : ctx_h;

    for (int e = t; e < 3200; e += 256) {
        int row = e / 25, g = e - row*25;
        *(float4*)&sv[row][4*g] =
            *(const float4*)(src + (size_t)(b*L + row)*(2*H) + dir*H + 4*g);
    }
    for (int e = t; e < 2048; e += 256) {
        int s = e >> 4, r = e & 15;
        cvT[s][r] = mat[s*L + r0 + r];
    }
    __syncthreads();

    const int tr = t & 7, th = t >> 3;   // 2 rows x 4 h per thread, th<25 active
    if (th < 25) {
        float acc[2][4], amx[2][4];
#pragma unroll
        for (int rr = 0; rr < 2; ++rr)
#pragma unroll
            for (int qq = 0; qq < 4; ++qq) { acc[rr][qq] = 0.f; amx[rr][qq] = -INFINITY; }
        for (int s = 0; s < L; ++s) {
            float2 c2 = *(const float2*)&cvT[s][2*tr];
            float4 v4 = *(const float4*)&sv[s][4*th];
            float cs[2] = {c2.x, c2.y};
            float vs[4] = {v4.x, v4.y, v4.z, v4.w};
#pragma unroll
            for (int rr = 0; rr < 2; ++rr)
#pragma unroll
                for (int qq = 0; qq < 4; ++qq) {
                    float pr = cs[rr] * vs[qq];
                    acc[rr][qq] += pr;
                    amx[rr][qq] = fmaxf(amx[rr][qq], pr);
                }
        }
        const float* den = side ? colsum : rowsum;
#pragma unroll
        for (int rr = 0; rr < 2; ++rr) {
            int rg = r0 + 2*tr + rr;
            float d = fmaxf(den[(dir*B + b)*L + rg], EPSF);
            float* meanp = attbuf + ((((size_t)side*2 + 0)*2 + dir)*B*L + (b*L + rg))*H + 4*th;
            float* maxp  = attbuf + ((((size_t)side*2 + 1)*2 + dir)*B*L + (b*L + rg))*H + 4*th;
            float4 fm; fm.x = acc[rr][0]/d; fm.y = acc[rr][1]/d; fm.z = acc[rr][2]/d; fm.w = acc[rr][3]/d;
            float4 fx; fx.x = amx[rr][0]; fx.y = amx[rr][1]; fx.z = amx[rr][2]; fx.w = amx[rr][3];
            *(float4*)meanp = fm;
            *(float4*)maxp  = fx;
        }
    }
}

// ================= dispatch 3: pointwise mpm =================
__global__ __launch_bounds__(128) void point_kernel(
    const float* __restrict__ ctx_p, const float* __restrict__ ctx_h,
    const float* __restrict__ w2t,
    const float* __restrict__ lastv, const float* __restrict__ attbuf,
    float* __restrict__ out)
{
    const int b = blockIdx.x, side = blockIdx.y;
    const int m = blockIdx.z >> 1, ih = blockIdx.z & 1;
    const int t = threadIdx.x;
    const int il = t & 63, half = t >> 6;
    const int i = ih*64 + il;
    const int dir = m & 1;
    const int wsel_[6] = {0, 1, 4, 5, 6, 7};
    const int chb_[6]  = {4, 25, 126, 147, 168, 189};

    const float* v1p = (side ? ctx_h : ctx_p) + (size_t)(b*L + i)*(2*H) + dir*H;
    const float* v2p;
    if (m < 2) {
        v2p = lastv + ((size_t)((side ? 0 : 2) + dir)*B + b)*H;
    } else {
        int kind = (m >= 4) ? 1 : 0;
        v2p = attbuf + ((((size_t)side*2 + kind)*2 + dir)*B*L + (b*L + i))*H;
    }
    const float* wt = w2t + (size_t)wsel_[m]*2100;

    float s11[21], s22[21], s12[21];
#pragma unroll
    for (int p = 0; p < 21; ++p) { s11[p] = 0.f; s22[p] = 0.f; s12[p] = 0.f; }
    const int g0 = half ? 13 : 0, g1 = half ? 25 : 13;
    for (int g = g0; g < g1; ++g) {
        float4 x = *(const float4*)(v1p + 4*g);
        float4 y = *(const float4*)(v2p + 4*g);
        float xx[4] = {x.x*x.x, x.y*x.y, x.z*x.z, x.w*x.w};
        float yy[4] = {y.x*y.x, y.y*y.y, y.z*y.z, y.w*y.w};
        float xy[4] = {x.x*y.x, x.y*y.y, x.z*y.z, x.w*y.w};
        const float* wg = wt + g*84;
#pragma unroll
        for (int hh = 0; hh < 4; ++hh)
#pragma unroll
            for (int p = 0; p < 21; ++p) {
                float w2 = wg[hh*21 + p];
                s11[p] = fmaf(w2, xx[hh], s11[p]);
                s22[p] = fmaf(w2, yy[hh], s22[p]);
                s12[p] = fmaf(w2, xy[hh], s12[p]);
            }
    }
    __shared__ float red[3][21][64];
    if (half) {
#pragma unroll
        for (int p = 0; p < 21; ++p) {
            red[0][p][il] = s11[p]; red[1][p][il] = s22[p]; red[2][p][il] = s12[p];
        }
    }
    __syncthreads();
    if (!half) {
        float* orow = out + (size_t)side*B*L*CH + (size_t)(b*L + i)*CH;
#pragma unroll
        for (int p = 0; p < 21; ++p) {
            float a = s11[p] + red[0][p][il];
            float c = s22[p] + red[1][p][il];
            float d = s12[p] + red[2][p][il];
            float cv = d / (fmaxf(sqrtf(a), EPSF) * fmaxf(sqrtf(c), EPSF));
            orow[(p == P) ? chb_[m] : (chb_[m] + 1 + p)] = cv;
        }
    }
}

extern "C" void kernel_launch(void* const* d_in, const int* in_sizes, int n_in,
                              void* d_out, int out_size, void* d_ws, size_t ws_size,
                              hipStream_t stream) {
    const float* ctx_p  = (const float*)d_in[0];
    const int*   mask_p = (const int*)d_in[1];
    const float* ctx_h  = (const float*)d_in[2];
    const int*   mask_h = (const int*)d_in[3];
    const float* params = (const float*)d_in[4];
    float* out = (float*)d_out;

    float* ws = (float*)d_ws;
    float* cosbuf = ws + OFF_COS;
    float* cosT   = ws + OFF_COST;
    float* rowsum = ws + OFF_ROWSUM;
    float* colsum = ws + OFF_COLSUM;
    float* lastv  = ws + OFF_LASTV;
    float* w2t    = ws + OFF_W2T;
    float* attbuf = ws + OFF_ATT;

    pair_kernel <<<dim3(705),      256, 0, stream>>>(ctx_p, ctx_h, mask_p, mask_h, params,
                                                     cosbuf, cosT, rowsum, colsum,
                                                     lastv, w2t, out);
    att_kernel  <<<dim3(B, 4, 8),  256, 0, stream>>>(ctx_p, ctx_h, cosbuf, cosT,
                                                     rowsum, colsum, attbuf);
    point_kernel<<<dim3(B, 2, 12), 128, 0, stream>>>(ctx_p, ctx_h, w2t, lastv, attbuf, out);
}

// Round 6
// 122.524 us; speedup vs baseline: 1.9126x; 1.1024x over previous
//
#include <hip/hip_runtime.h>
#include <math.h>

#define B 16
#define L 128
#define H 100
#define P 20
#define CH 210
#define EPSF 1e-8f

// workspace layout (float offsets)
#define OFF_COS    0u         // [dir][b][i][j]            524288
#define OFF_COST   524288u    // [dir][b][j][i]            524288
#define OFF_ROWSUM 1048576u   // [dir][b][i]               4096
#define OFF_COLSUM 1052672u   // [dir][b][j]               4096
#define OFF_LASTV  1056768u   // [is_h*2+dir][b][h]        6400
#define OFF_W2T    1063168u   // [m8][h100][p21] w^2       16800 (p==20 -> 1.0)

typedef __attribute__((ext_vector_type(8))) short bf16x8;
typedef __attribute__((ext_vector_type(4))) float f32x4;

__device__ inline unsigned short f2bf(float x) {   // RNE float->bf16 bits
    union { float f; unsigned u; } c; c.f = x;
    unsigned r = c.u + 0x7fffu + ((c.u >> 16) & 1u);
    return (unsigned short)(r >> 16);
}

// ================= dispatch 1: pair (672 tasks) + w2t (1 blk) + lastv (32 blks) ========
// LDS: sB 32768 + colred 4096 + nlds 1024 = 37888 B  (unchanged from R5 -- known good)
__global__ __launch_bounds__(256, 2) void pair_kernel(
    const float* __restrict__ ctx_p, const float* __restrict__ ctx_h,
    const int* __restrict__ mask_p, const int* __restrict__ mask_h,
    const float* __restrict__ params,
    float* __restrict__ cosbuf, float* __restrict__ cosT,
    float* __restrict__ rowsum, float* __restrict__ colsum,
    float* __restrict__ lastv, float* __restrict__ w2t,
    float* __restrict__ out)
{
    __shared__ __align__(16) char smem[37888];
    const int k = blockIdx.x, t = threadIdx.x;

    if (k >= 672) {
        if (k == 672) {
            // w2t [m][h][p]; p==20 -> 1.0 (consumed next dispatch)
            for (int e = t; e < 16800; e += 256) {
                int m = e / 2100, r = e % 2100;
                int h = r / 21, p = r % 21;
                float v = 1.f;
                if (p < P) { float w = params[((size_t)m*P + p)*H + h]; v = w*w; }
                w2t[e] = v;
            }
        } else {
            // lastv task: b, is_h
            const int task = k - 673, b = task >> 1, is_h = task & 1;
            const float* ctx = is_h ? ctx_h : ctx_p;
            const int* mask = is_h ? mask_h : mask_p;
            int* sm = (int*)smem;
            if (t < 128) sm[t] = mask[b*L + t];
            __syncthreads();
            for (int s = 64; s > 0; s >>= 1) {
                if (t < s) sm[t] += sm[t + s];
                __syncthreads();
            }
            int last = sm[0] - 1;
            if (last < 0) last = 0;
            if (t < H) {
                lastv[((size_t)(is_h*2 + 0)*B + b)*H + t] = ctx[(size_t)(b*L + last)*(2*H) + t];
                lastv[((size_t)(is_h*2 + 1)*B + b)*H + t] = ctx[(size_t)(b*L + 0)*(2*H) + H + t];
            }
        }
        return;
    }

    // ---- pair task (b, dir, p) ----
    const int b = k & 15, dir = (k >> 4) & 1, p = k >> 5;
    short* sB     = (short*)smem;                 // frag (cg*4+kt)*64+lane, 8 bf16
    float* colred = (float*)(smem + 32768);       // [kind2][wave4][col128]
    float* nlds   = (float*)(smem + 32768 + 4096);// [side2][row128]

    // stage B (ctx_h dir-half) into MFMA frag layout; zero-pad k>=100
    for (int e = t; e < 2048; e += 256) {
        int cgi = e >> 8, kt = (e >> 6) & 3, qq = (e >> 4) & 3, rl2 = e & 15;
        int row = cgi*16 + rl2, kb = kt*32 + qq*8;
        float v[8];
#pragma unroll
        for (int j = 0; j < 8; ++j) v[j] = 0.f;
        const float* src = ctx_h + (size_t)(b*L + row)*(2*H) + dir*H;
        if (kb < H)     { float4 f = *(const float4*)(src + kb);     v[0]=f.x; v[1]=f.y; v[2]=f.z; v[3]=f.w; }
        if (kb + 4 < H) { float4 f = *(const float4*)(src + kb + 4); v[4]=f.x; v[5]=f.y; v[6]=f.z; v[7]=f.w; }
        bf16x8 pk;
#pragma unroll
        for (int j = 0; j < 8; ++j) pk[j] = (short)f2bf(v[j]);
        *(bf16x8*)&sB[e*8] = pk;
    }

    const float* prow = params + ((size_t)(2 + dir)*P + p)*H;   // valid only when p<20

    // A frags: global->reg direct, scaled by w^2_p
    const int w = t >> 6, lane = t & 63, q = lane >> 4, rl = lane & 15;
    bf16x8 af[2][4];
#pragma unroll
    for (int rgi = 0; rgi < 2; ++rgi) {
        int row = (w*2 + rgi)*16 + rl;
        const float* src = ctx_p + (size_t)(b*L + row)*(2*H) + dir*H;
#pragma unroll
        for (int kt = 0; kt < 4; ++kt) {
            int kb = kt*32 + q*8;
            float v[8];
#pragma unroll
            for (int j = 0; j < 8; ++j) v[j] = 0.f;
            if (p < P) {
                if (kb < H) {
                    float4 f = *(const float4*)(src + kb);
                    float4 wv = *(const float4*)(prow + kb);
                    v[0]=f.x*wv.x*wv.x; v[1]=f.y*wv.y*wv.y; v[2]=f.z*wv.z*wv.z; v[3]=f.w*wv.w*wv.w;
                }
                if (kb + 4 < H) {
                    float4 f = *(const float4*)(src + kb + 4);
                    float4 wv = *(const float4*)(prow + kb + 4);
                    v[4]=f.x*wv.x*wv.x; v[5]=f.y*wv.y*wv.y; v[6]=f.z*wv.z*wv.z; v[7]=f.w*wv.w*wv.w;
                }
            } else {
                if (kb < H)     { float4 f = *(const float4*)(src + kb);     v[0]=f.x; v[1]=f.y; v[2]=f.z; v[3]=f.w; }
                if (kb + 4 < H) { float4 f = *(const float4*)(src + kb + 4); v[4]=f.x; v[5]=f.y; v[6]=f.z; v[7]=f.w; }
            }
            bf16x8 pk;
#pragma unroll
            for (int j = 0; j < 8; ++j) pk[j] = (short)f2bf(v[j]);
            af[rgi][kt] = pk;
        }
    }

    // in-block weighted norms (fp32-exact): thread t -> row t&127 of side t>>7
    {
        const int r = t & 127, sd = t >> 7;
        const float* nrow = (sd ? ctx_h : ctx_p) + (size_t)(b*L + r)*(2*H) + dir*H;
        float n2 = 0.f;
        if (p < P) {
            for (int g = 0; g < 25; ++g) {
                float4 v = *(const float4*)(nrow + 4*g);
                float4 wv = *(const float4*)(prow + 4*g);
                n2 = fmaf(wv.x*wv.x, v.x*v.x, n2);
                n2 = fmaf(wv.y*wv.y, v.y*v.y, n2);
                n2 = fmaf(wv.z*wv.z, v.z*v.z, n2);
                n2 = fmaf(wv.w*wv.w, v.w*v.w, n2);
            }
        } else {
            for (int g = 0; g < 25; ++g) {
                float4 v = *(const float4*)(nrow + 4*g);
                n2 = fmaf(v.x, v.x, n2); n2 = fmaf(v.y, v.y, n2);
                n2 = fmaf(v.z, v.z, n2); n2 = fmaf(v.w, v.w, n2);
            }
        }
        nlds[sd*128 + r] = sqrtf(n2);
    }
    __syncthreads();

    f32x4 acc[2][8];
#pragma unroll
    for (int rgi = 0; rgi < 2; ++rgi)
#pragma unroll
        for (int cgi = 0; cgi < 8; ++cgi) acc[rgi][cgi] = (f32x4)0.f;
#pragma unroll
    for (int kt = 0; kt < 4; ++kt) {
#pragma unroll
        for (int cgi = 0; cgi < 8; ++cgi) {
            bf16x8 bfr = *(bf16x8*)&sB[((cgi*4 + kt)*64 + lane)*8];
            acc[0][cgi] = __builtin_amdgcn_mfma_f32_16x16x32_bf16(af[0][kt], bfr, acc[0][cgi], 0, 0, 0);
            acc[1][cgi] = __builtin_amdgcn_mfma_f32_16x16x32_bf16(af[1][kt], bfr, acc[1][cgi], 0, 0, 0);
        }
    }

    float na[2][4];
#pragma unroll
    for (int rgi = 0; rgi < 2; ++rgi)
#pragma unroll
        for (int r = 0; r < 4; ++r) na[rgi][r] = nlds[0*128 + (w*2 + rgi)*16 + q*4 + r];
    float nbv[8];
#pragma unroll
    for (int cgi = 0; cgi < 8; ++cgi) nbv[cgi] = nlds[1*128 + cgi*16 + rl];

    const bool iscos = (p == P);
    float* cosm  = cosbuf + (size_t)(dir*B + b)*16384;
    float* cosmT = cosT   + (size_t)(dir*B + b)*16384;

    int chmax, chmean;
    if (p < P) { chmax = (dir ? 86 : 46) + p; chmean = (dir ? 106 : 66) + p; }
    else       { chmax = dir*2;              chmean = dir*2 + 1; }

    float rowm[2][4], rows_[2][4], colm[8], cols_[8];
#pragma unroll
    for (int rgi = 0; rgi < 2; ++rgi)
#pragma unroll
        for (int r = 0; r < 4; ++r) { rowm[rgi][r] = -INFINITY; rows_[rgi][r] = 0.f; }
#pragma unroll
    for (int cgi = 0; cgi < 8; ++cgi) { colm[cgi] = -INFINITY; cols_[cgi] = 0.f; }

#pragma unroll
    for (int rgi = 0; rgi < 2; ++rgi) {
        int i0 = (w*2 + rgi)*16 + q*4;
#pragma unroll
        for (int cgi = 0; cgi < 8; ++cgi) {
            float m[4];
#pragma unroll
            for (int r = 0; r < 4; ++r) {
                float d = fmaxf(na[rgi][r]*nbv[cgi], EPSF);
                m[r] = acc[rgi][cgi][r] * __builtin_amdgcn_rcpf(d);
                rowm[rgi][r] = fmaxf(rowm[rgi][r], m[r]);
                rows_[rgi][r] += m[r];
            }
            float cM = fmaxf(fmaxf(m[0], m[1]), fmaxf(m[2], m[3]));
            colm[cgi] = fmaxf(colm[cgi], cM);
            cols_[cgi] += (m[0] + m[1]) + (m[2] + m[3]);
            if (iscos) {
                int j = cgi*16 + rl;
                float4 f4; f4.x = m[0]; f4.y = m[1]; f4.z = m[2]; f4.w = m[3];
                *(float4*)&cosmT[j*128 + i0] = f4;
#pragma unroll
                for (int r = 0; r < 4; ++r) cosm[(i0 + r)*128 + j] = m[r];
            }
        }
    }
#pragma unroll
    for (int rgi = 0; rgi < 2; ++rgi)
#pragma unroll
        for (int r = 0; r < 4; ++r) {
            float mx = rowm[rgi][r], sm = rows_[rgi][r];
#pragma unroll
            for (int d = 1; d < 16; d <<= 1) {
                mx = fmaxf(mx, __shfl_xor(mx, d));
                sm += __shfl_xor(sm, d);
            }
            if (rl == 0) {
                int i = (w*2 + rgi)*16 + q*4 + r;
                float* orow = out + (size_t)(b*L + i)*CH;
                orow[chmax] = mx; orow[chmean] = sm * (1.f/L);
                if (iscos) rowsum[(dir*B + b)*L + i] = sm;
            }
        }
#pragma unroll
    for (int cgi = 0; cgi < 8; ++cgi) {
        float mx = colm[cgi], sm = cols_[cgi];
        mx = fmaxf(mx, __shfl_xor(mx, 16)); sm += __shfl_xor(sm, 16);
        mx = fmaxf(mx, __shfl_xor(mx, 32)); sm += __shfl_xor(sm, 32);
        if (q == 0) {
            colred[(0*4 + w)*128 + cgi*16 + rl] = mx;
            colred[(1*4 + w)*128 + cgi*16 + rl] = sm;
        }
    }
    __syncthreads();
    {
        int c = t & 127, kind = t >> 7;
        float v0 = colred[(kind*4 + 0)*128 + c], v1 = colred[(kind*4 + 1)*128 + c];
        float v2 = colred[(kind*4 + 2)*128 + c], v3 = colred[(kind*4 + 3)*128 + c];
        float* oh = out + (size_t)B*L*CH + (size_t)(b*L + c)*CH;
        if (kind == 0) {
            oh[chmax] = fmaxf(fmaxf(v0, v1), fmaxf(v2, v3));
        } else {
            float sm = (v0 + v1) + (v2 + v3);
            oh[chmean] = sm * (1.f/L);
            if (iscos) colsum[(dir*B + b)*L + c] = sm;
        }
    }
}

// ================= dispatch 2: att vectors + fused att-mpm + lastv-mpm =================
// blocks 0..511: att task (b, side, dir, rc) -> att mean/max for 16 rows, then the
//   21-perspective cos-sims (out ch 126..209) computed IN-BLOCK (no attbuf).
// blocks 512..575: point m0/1 (lastv-based, out ch 4..45).
__global__ __launch_bounds__(256, 2) void attpoint_kernel(
    const float* __restrict__ ctx_p, const float* __restrict__ ctx_h,
    const float* __restrict__ cosbuf, const float* __restrict__ cosT,
    const float* __restrict__ rowsum, const float* __restrict__ colsum,
    const float* __restrict__ lastv, const float* __restrict__ w2t,
    float* __restrict__ out)
{
    __shared__ __align__(16) char smem[59392];
    const int k = blockIdx.x, t = threadIdx.x;

    if (k >= 512) {
        // ---- point m0/1: task (b, side, m) ----
        const int task = k - 512;
        const int b = task & 15, side = (task >> 4) & 1, m = task >> 5;  // m = dir
        const int i = t & 127, half = t >> 7;
        const int chb = m ? 25 : 4;
        const float* v1p = (side ? ctx_h : ctx_p) + (size_t)(b*L + i)*(2*H) + m*H;
        const float* v2p = lastv + ((size_t)((side ? 0 : 2) + m)*B + b)*H;
        const float* wt = w2t + (size_t)m*2100;

        float s11[21], s22[21], s12[21];
#pragma unroll
        for (int p = 0; p < 21; ++p) { s11[p] = 0.f; s22[p] = 0.f; s12[p] = 0.f; }
        const int g0 = half ? 13 : 0, g1 = half ? 25 : 13;
        for (int g = g0; g < g1; ++g) {
            float4 x = *(const float4*)(v1p + 4*g);
            float4 y = *(const float4*)(v2p + 4*g);
            float xx[4] = {x.x*x.x, x.y*x.y, x.z*x.z, x.w*x.w};
            float yy[4] = {y.x*y.x, y.y*y.y, y.z*y.z, y.w*y.w};
            float xy[4] = {x.x*y.x, x.y*y.y, x.z*y.z, x.w*y.w};
            const float* wg = wt + g*84;
#pragma unroll
            for (int hh = 0; hh < 4; ++hh)
#pragma unroll
                for (int p = 0; p < 21; ++p) {
                    float w2 = wg[hh*21 + p];
                    s11[p] = fmaf(w2, xx[hh], s11[p]);
                    s22[p] = fmaf(w2, yy[hh], s22[p]);
                    s12[p] = fmaf(w2, xy[hh], s12[p]);
                }
        }
        float* red = (float*)smem;   // [3][21][128]
        if (half) {
#pragma unroll
            for (int p = 0; p < 21; ++p) {
                red[(0*21 + p)*128 + i] = s11[p];
                red[(1*21 + p)*128 + i] = s22[p];
                red[(2*21 + p)*128 + i] = s12[p];
            }
        }
        __syncthreads();
        if (!half) {
            float* orow = out + (size_t)side*B*L*CH + (size_t)(b*L + i)*CH;
#pragma unroll
            for (int p = 0; p < 21; ++p) {
                float a = s11[p] + red[(0*21 + p)*128 + i];
                float c = s22[p] + red[(1*21 + p)*128 + i];
                float d = s12[p] + red[(2*21 + p)*128 + i];
                float cv = d / (fmaxf(sqrtf(a), EPSF) * fmaxf(sqrtf(c), EPSF));
                orow[(p == P) ? chb : (chb + 1 + p)] = cv;
            }
        }
        return;
    }

    // ---- att task (b, side, dir, rc) ----
    const int b = k & 15, side = (k >> 4) & 1, dir = (k >> 5) & 1, rc = k >> 6;
    const int r0 = rc*16;
    float* sf = (float*)smem;
    float (*sv)[100] = (float(*)[100])smem;            // 51200 B (j-side vectors)
    float (*cvT)[16] = (float(*)[16])(smem + 51200);   // 8192 B

    const float* mat = (side ? cosbuf : cosT) + (size_t)(dir*B + b)*16384;
    const float* srcJ = side ? ctx_p : ctx_h;   // vectors being attended over
    const float* srcI = side ? ctx_h : ctx_p;   // v1 rows (out side)

    for (int e = t; e < 3200; e += 256) {
        int row = e / 25, g = e - row*25;
        *(float4*)&sv[row][4*g] =
            *(const float4*)(srcJ + (size_t)(b*L + row)*(2*H) + dir*H + 4*g);
    }
    for (int e = t; e < 2048; e += 256) {
        int s = e >> 4, r = e & 15;
        cvT[s][r] = mat[s*L + r0 + r];
    }
    __syncthreads();

    const int tr = t & 7, th = t >> 3;   // 2 rows x 4 h per thread, th<25 active
    float acc[2][4], amx[2][4];
#pragma unroll
    for (int rr = 0; rr < 2; ++rr)
#pragma unroll
        for (int qq = 0; qq < 4; ++qq) { acc[rr][qq] = 0.f; amx[rr][qq] = -INFINITY; }
    if (th < 25) {
        for (int s = 0; s < L; ++s) {
            float2 c2 = *(const float2*)&cvT[s][2*tr];
            float4 v4 = *(const float4*)&sv[s][4*th];
            float cs[2] = {c2.x, c2.y};
            float vs[4] = {v4.x, v4.y, v4.z, v4.w};
#pragma unroll
            for (int rr = 0; rr < 2; ++rr)
#pragma unroll
                for (int qq = 0; qq < 4; ++qq) {
                    float pr = cs[rr] * vs[qq];
                    acc[rr][qq] += pr;
                    amx[rr][qq] = fmaxf(amx[rr][qq], pr);
                }
        }
    }
    __syncthreads();   // all sv/cvT reads done -> region reusable

    // overlay (floats, within old sv region; 12000 <= 12800 floats):
    float* attv = sf;           // [kind2][row16][h100]        3200
    float* v1s  = sf + 3200;    // [row16][h100]               1600
    float* w2l  = sf + 4800;    // [kind2][h100][36] (21 used) 7200
    if (th < 25) {
        const float* den = side ? colsum : rowsum;
#pragma unroll
        for (int rr = 0; rr < 2; ++rr) {
            int rloc = 2*tr + rr;
            float d = fmaxf(den[(dir*B + b)*L + r0 + rloc], EPSF);
            float inv = 1.f / d;
#pragma unroll
            for (int qq = 0; qq < 4; ++qq) {
                attv[0*1600 + rloc*100 + 4*th + qq] = acc[rr][qq] * inv;
                attv[1*1600 + rloc*100 + 4*th + qq] = amx[rr][qq];
            }
        }
    }
    for (int e = t; e < 400; e += 256) {
        int row = e / 25, g = e - row*25;
        *(float4*)&v1s[row*100 + 4*g] =
            *(const float4*)(srcI + (size_t)(b*L + r0 + row)*(2*H) + dir*H + 4*g);
    }
    // w2 tables: kind0 (mean) -> params[4+dir], kind1 (max) -> params[6+dir]
    for (int e = t; e < 4200; e += 256) {
        int kind = e >= 2100 ? 1 : 0, r = e - kind*2100;
        int h = r / 21, p = r - h*21;
        int wsel = 4 + kind*2 + dir;
        w2l[kind*3600 + h*36 + p] = w2t[(size_t)wsel*2100 + r];
    }
    __syncthreads();

    // phase C: 32 tasks (kind2 x row16) x 8 h-strip lanes
    {
        const int task = t >> 3, tt = t & 7;
        const int kind = task >> 4, row = task & 15;
        const int h0 = tt*13, cnt = (tt < 7) ? 13 : 9;
        const float* av  = attv + kind*1600 + row*100;
        const float* v1r = v1s + row*100;
        const float* wk  = w2l + kind*3600;

        float s11[21], s22[21], s12[21];
#pragma unroll
        for (int p = 0; p < 21; ++p) { s11[p] = 0.f; s22[p] = 0.f; s12[p] = 0.f; }
        for (int hh = 0; hh < cnt; ++hh) {
            int h = h0 + hh;
            float a = v1r[h], c = av[h];
            float xx = a*a, yy = c*c, xy = a*c;
            const float* wrow = wk + h*36;   // 16B-aligned (36*4=144)
#pragma unroll
            for (int pg = 0; pg < 5; ++pg) {
                float4 wv = *(const float4*)&wrow[4*pg];
                float ws[4] = {wv.x, wv.y, wv.z, wv.w};
#pragma unroll
                for (int q = 0; q < 4; ++q) {
                    int p = 4*pg + q;
                    s11[p] = fmaf(ws[q], xx, s11[p]);
                    s22[p] = fmaf(ws[q], yy, s22[p]);
                    s12[p] = fmaf(ws[q], xy, s12[p]);
                }
            }
            float w20 = wrow[20];
            s11[20] = fmaf(w20, xx, s11[20]);
            s22[20] = fmaf(w20, yy, s22[20]);
            s12[20] = fmaf(w20, xy, s12[20]);
        }
        // reduce over the 8 strip lanes (consecutive lanes, xor 1/2/4)
#pragma unroll
        for (int p = 0; p < 21; ++p) {
#pragma unroll
            for (int d = 1; d < 8; d <<= 1) {
                s11[p] += __shfl_xor(s11[p], d);
                s22[p] += __shfl_xor(s22[p], d);
                s12[p] += __shfl_xor(s12[p], d);
            }
        }
        if (tt == 0) {
            // kind0 -> m=2+dir (ch 126/147), kind1 -> m=4+dir (ch 168/189)
            int chb = kind ? (dir ? 189 : 168) : (dir ? 147 : 126);
            float* orow = out + (size_t)side*B*L*CH + (size_t)(b*L + r0 + row)*CH;
#pragma unroll
            for (int p = 0; p < 21; ++p) {
                float cv = s12[p] / (fmaxf(sqrtf(s11[p]), EPSF) * fmaxf(sqrtf(s22[p]), EPSF));
                orow[(p == P) ? chb : (chb + 1 + p)] = cv;
            }
        }
    }
}

extern "C" void kernel_launch(void* const* d_in, const int* in_sizes, int n_in,
                              void* d_out, int out_size, void* d_ws, size_t ws_size,
                              hipStream_t stream) {
    const float* ctx_p  = (const float*)d_in[0];
    const int*   mask_p = (const int*)d_in[1];
    const float* ctx_h  = (const float*)d_in[2];
    const int*   mask_h = (const int*)d_in[3];
    const float* params = (const float*)d_in[4];
    float* out = (float*)d_out;

    float* ws = (float*)d_ws;
    float* cosbuf = ws + OFF_COS;
    float* cosT   = ws + OFF_COST;
    float* rowsum = ws + OFF_ROWSUM;
    float* colsum = ws + OFF_COLSUM;
    float* lastv  = ws + OFF_LASTV;
    float* w2t    = ws + OFF_W2T;

    pair_kernel    <<<dim3(705), 256, 0, stream>>>(ctx_p, ctx_h, mask_p, mask_h, params,
                                                   cosbuf, cosT, rowsum, colsum,
                                                   lastv, w2t, out);
    attpoint_kernel<<<dim3(576), 256, 0, stream>>>(ctx_p, ctx_h, cosbuf, cosT,
                                                   rowsum, colsum, lastv, w2t, out);
}

// Round 7
// 121.696 us; speedup vs baseline: 1.9256x; 1.0068x over previous
//
#include <hip/hip_runtime.h>
#include <math.h>

#define B 16
#define L 128
#define H 100
#define P 20
#define CH 210
#define EPSF 1e-8f
#define MAGIC 0x13579BDF

// workspace layout (float offsets): cos 2MB + cosT 2MB + 32 flags
#define OFF_COS   0u
#define OFF_COST  524288u
#define OFF_FLAGS 1048576u

typedef __attribute__((ext_vector_type(8))) short bf16x8;
typedef __attribute__((ext_vector_type(4))) float f32x4;

__device__ inline unsigned short f2bf(float x) {   // RNE float->bf16 bits
    union { float f; unsigned u; } c; c.f = x;
    unsigned r = c.u + 0x7fffu + ((c.u >> 16) & 1u);
    return (unsigned short)(r >> 16);
}

// ONE dispatch. blocks 0..31: pair p==20 (cos producers, set flags);
// 32..671: pair p<20; 672..1183: att (spin on flag); 1184..1247: point m0/1.
__global__ __launch_bounds__(256, 2) void fused_kernel(
    const float* __restrict__ ctx_p, const int* __restrict__ mask_p,
    const float* __restrict__ ctx_h, const int* __restrict__ mask_h,
    const float* __restrict__ params,
    float* __restrict__ cosbuf, float* __restrict__ cosT,
    int* __restrict__ flags, float* __restrict__ out)
{
    __shared__ __align__(16) char smem[59904];
    const int k = blockIdx.x, t = threadIdx.x;

    if (k < 672) {
        // ================= pair task (b, dir, p) =================
        int b, dir, p;
        if (k < 32) { b = k & 15; dir = k >> 4; p = P; }
        else { int idx = k - 32; b = idx & 15; dir = (idx >> 4) & 1; p = idx >> 5; }

        short* sB     = (short*)smem;                 // 32768 B frag (cg*4+kt)*64+lane
        float* colred = (float*)(smem + 32768);       // [kind2][wave4][col128]
        float* nlds   = (float*)(smem + 32768 + 4096);// [side2][row128]

        // stage B (ctx_h dir-half) into MFMA frag layout; zero-pad k>=100
        for (int e = t; e < 2048; e += 256) {
            int cgi = e >> 8, kt = (e >> 6) & 3, qq = (e >> 4) & 3, rl2 = e & 15;
            int row = cgi*16 + rl2, kb = kt*32 + qq*8;
            float v[8];
#pragma unroll
            for (int j = 0; j < 8; ++j) v[j] = 0.f;
            const float* src = ctx_h + (size_t)(b*L + row)*(2*H) + dir*H;
            if (kb < H)     { float4 f = *(const float4*)(src + kb);     v[0]=f.x; v[1]=f.y; v[2]=f.z; v[3]=f.w; }
            if (kb + 4 < H) { float4 f = *(const float4*)(src + kb + 4); v[4]=f.x; v[5]=f.y; v[6]=f.z; v[7]=f.w; }
            bf16x8 pk;
#pragma unroll
            for (int j = 0; j < 8; ++j) pk[j] = (short)f2bf(v[j]);
            *(bf16x8*)&sB[e*8] = pk;
        }

        const float* prow = params + ((size_t)(2 + dir)*P + p)*H;   // used only when p<20

        // A frags: global->reg direct, scaled by w^2_p
        const int w = t >> 6, lane = t & 63, q = lane >> 4, rl = lane & 15;
        bf16x8 af[2][4];
#pragma unroll
        for (int rgi = 0; rgi < 2; ++rgi) {
            int row = (w*2 + rgi)*16 + rl;
            const float* src = ctx_p + (size_t)(b*L + row)*(2*H) + dir*H;
#pragma unroll
            for (int kt = 0; kt < 4; ++kt) {
                int kb = kt*32 + q*8;
                float v[8];
#pragma unroll
                for (int j = 0; j < 8; ++j) v[j] = 0.f;
                if (p < P) {
                    if (kb < H) {
                        float4 f = *(const float4*)(src + kb);
                        float4 wv = *(const float4*)(prow + kb);
                        v[0]=f.x*wv.x*wv.x; v[1]=f.y*wv.y*wv.y; v[2]=f.z*wv.z*wv.z; v[3]=f.w*wv.w*wv.w;
                    }
                    if (kb + 4 < H) {
                        float4 f = *(const float4*)(src + kb + 4);
                        float4 wv = *(const float4*)(prow + kb + 4);
                        v[4]=f.x*wv.x*wv.x; v[5]=f.y*wv.y*wv.y; v[6]=f.z*wv.z*wv.z; v[7]=f.w*wv.w*wv.w;
                    }
                } else {
                    if (kb < H)     { float4 f = *(const float4*)(src + kb);     v[0]=f.x; v[1]=f.y; v[2]=f.z; v[3]=f.w; }
                    if (kb + 4 < H) { float4 f = *(const float4*)(src + kb + 4); v[4]=f.x; v[5]=f.y; v[6]=f.z; v[7]=f.w; }
                }
                bf16x8 pk;
#pragma unroll
                for (int j = 0; j < 8; ++j) pk[j] = (short)f2bf(v[j]);
                af[rgi][kt] = pk;
            }
        }

        // in-block weighted norms (fp32-exact)
        {
            const int r = t & 127, sd = t >> 7;
            const float* nrow = (sd ? ctx_h : ctx_p) + (size_t)(b*L + r)*(2*H) + dir*H;
            float n2 = 0.f;
            if (p < P) {
                for (int g = 0; g < 25; ++g) {
                    float4 v = *(const float4*)(nrow + 4*g);
                    float4 wv = *(const float4*)(prow + 4*g);
                    n2 = fmaf(wv.x*wv.x, v.x*v.x, n2);
                    n2 = fmaf(wv.y*wv.y, v.y*v.y, n2);
                    n2 = fmaf(wv.z*wv.z, v.z*v.z, n2);
                    n2 = fmaf(wv.w*wv.w, v.w*v.w, n2);
                }
            } else {
                for (int g = 0; g < 25; ++g) {
                    float4 v = *(const float4*)(nrow + 4*g);
                    n2 = fmaf(v.x, v.x, n2); n2 = fmaf(v.y, v.y, n2);
                    n2 = fmaf(v.z, v.z, n2); n2 = fmaf(v.w, v.w, n2);
                }
            }
            nlds[sd*128 + r] = sqrtf(n2);
        }
        __syncthreads();

        f32x4 acc[2][8];
#pragma unroll
        for (int rgi = 0; rgi < 2; ++rgi)
#pragma unroll
            for (int cgi = 0; cgi < 8; ++cgi) acc[rgi][cgi] = (f32x4)0.f;
#pragma unroll
        for (int kt = 0; kt < 4; ++kt) {
#pragma unroll
            for (int cgi = 0; cgi < 8; ++cgi) {
                bf16x8 bfr = *(bf16x8*)&sB[((cgi*4 + kt)*64 + lane)*8];
                acc[0][cgi] = __builtin_amdgcn_mfma_f32_16x16x32_bf16(af[0][kt], bfr, acc[0][cgi], 0, 0, 0);
                acc[1][cgi] = __builtin_amdgcn_mfma_f32_16x16x32_bf16(af[1][kt], bfr, acc[1][cgi], 0, 0, 0);
            }
        }

        float na[2][4];
#pragma unroll
        for (int rgi = 0; rgi < 2; ++rgi)
#pragma unroll
            for (int r = 0; r < 4; ++r) na[rgi][r] = nlds[0*128 + (w*2 + rgi)*16 + q*4 + r];
        float nbv[8];
#pragma unroll
        for (int cgi = 0; cgi < 8; ++cgi) nbv[cgi] = nlds[1*128 + cgi*16 + rl];

        const bool iscos = (p == P);
        float* cosm  = cosbuf + (size_t)(dir*B + b)*16384;
        float* cosmT = cosT   + (size_t)(dir*B + b)*16384;

        int chmax, chmean;
        if (p < P) { chmax = (dir ? 86 : 46) + p; chmean = (dir ? 106 : 66) + p; }
        else       { chmax = dir*2;              chmean = dir*2 + 1; }

        float rowm[2][4], rows_[2][4], colm[8], cols_[8];
#pragma unroll
        for (int rgi = 0; rgi < 2; ++rgi)
#pragma unroll
            for (int r = 0; r < 4; ++r) { rowm[rgi][r] = -INFINITY; rows_[rgi][r] = 0.f; }
#pragma unroll
        for (int cgi = 0; cgi < 8; ++cgi) { colm[cgi] = -INFINITY; cols_[cgi] = 0.f; }

#pragma unroll
        for (int rgi = 0; rgi < 2; ++rgi) {
            int i0 = (w*2 + rgi)*16 + q*4;
#pragma unroll
            for (int cgi = 0; cgi < 8; ++cgi) {
                float m[4];
#pragma unroll
                for (int r = 0; r < 4; ++r) {
                    float d = fmaxf(na[rgi][r]*nbv[cgi], EPSF);
                    m[r] = acc[rgi][cgi][r] * __builtin_amdgcn_rcpf(d);
                    rowm[rgi][r] = fmaxf(rowm[rgi][r], m[r]);
                    rows_[rgi][r] += m[r];
                }
                float cM = fmaxf(fmaxf(m[0], m[1]), fmaxf(m[2], m[3]));
                colm[cgi] = fmaxf(colm[cgi], cM);
                cols_[cgi] += (m[0] + m[1]) + (m[2] + m[3]);
                if (iscos) {
                    int j = cgi*16 + rl;
                    float4 f4; f4.x = m[0]; f4.y = m[1]; f4.z = m[2]; f4.w = m[3];
                    *(float4*)&cosmT[j*128 + i0] = f4;
#pragma unroll
                    for (int r = 0; r < 4; ++r) cosm[(i0 + r)*128 + j] = m[r];
                }
            }
        }
#pragma unroll
        for (int rgi = 0; rgi < 2; ++rgi)
#pragma unroll
            for (int r = 0; r < 4; ++r) {
                float mx = rowm[rgi][r], sm = rows_[rgi][r];
#pragma unroll
                for (int d = 1; d < 16; d <<= 1) {
                    mx = fmaxf(mx, __shfl_xor(mx, d));
                    sm += __shfl_xor(sm, d);
                }
                if (rl == 0) {
                    int i = (w*2 + rgi)*16 + q*4 + r;
                    float* orow = out + (size_t)(b*L + i)*CH;
                    orow[chmax] = mx; orow[chmean] = sm * (1.f/L);
                }
            }
#pragma unroll
        for (int cgi = 0; cgi < 8; ++cgi) {
            float mx = colm[cgi], sm = cols_[cgi];
            mx = fmaxf(mx, __shfl_xor(mx, 16)); sm += __shfl_xor(sm, 16);
            mx = fmaxf(mx, __shfl_xor(mx, 32)); sm += __shfl_xor(sm, 32);
            if (q == 0) {
                colred[(0*4 + w)*128 + cgi*16 + rl] = mx;
                colred[(1*4 + w)*128 + cgi*16 + rl] = sm;
            }
        }
        if (iscos) __threadfence();   // make this thread's cos/cosT device-visible
        __syncthreads();
        if (iscos && t == 0)
            __hip_atomic_store(&flags[dir*16 + b], (int)MAGIC,
                               __ATOMIC_RELEASE, __HIP_MEMORY_SCOPE_AGENT);
        {
            int c = t & 127, kind = t >> 7;
            float v0 = colred[(kind*4 + 0)*128 + c], v1 = colred[(kind*4 + 1)*128 + c];
            float v2 = colred[(kind*4 + 2)*128 + c], v3 = colred[(kind*4 + 3)*128 + c];
            float* oh = out + (size_t)B*L*CH + (size_t)(b*L + c)*CH;
            if (kind == 0) {
                oh[chmax] = fmaxf(fmaxf(v0, v1), fmaxf(v2, v3));
            } else {
                float sm = (v0 + v1) + (v2 + v3);
                oh[chmean] = sm * (1.f/L);
            }
        }
        return;
    }

    if (k < 1184) {
        // ================= att task (b, side, dir, rc) =================
        const int idx = k - 672;
        const int b = idx & 15, side = (idx >> 4) & 1, dir = (idx >> 5) & 1, rc = idx >> 6;
        const int r0 = rc*16;
        float* sf = (float*)smem;
        float (*sv)[100] = (float(*)[100])smem;            // 51200 B (j-side vectors)
        float (*cvT)[16] = (float(*)[16])(smem + 51200);   // 8192 B
        float (*denred)[16] = (float(*)[16])(smem + 59392);// [8][16] 512 B

        const float* mat = (side ? cosbuf : cosT) + (size_t)(dir*B + b)*16384;
        const float* srcJ = side ? ctx_p : ctx_h;
        const float* srcI = side ? ctx_h : ctx_p;

        // stage sv first (no dependency) to overlap with producer completion
        for (int e = t; e < 3200; e += 256) {
            int row = e / 25, g = e - row*25;
            *(float4*)&sv[row][4*g] =
                *(const float4*)(srcJ + (size_t)(b*L + row)*(2*H) + dir*H + 4*g);
        }
        if (t == 0) {
            while (__hip_atomic_load(&flags[dir*16 + b],
                                     __ATOMIC_ACQUIRE, __HIP_MEMORY_SCOPE_AGENT) != (int)MAGIC)
                __builtin_amdgcn_s_sleep(2);
        }
        __syncthreads();   // sv staged + flag observed (acquire)

        for (int e = t; e < 2048; e += 256) {
            int s = e >> 4, r = e & 15;
            cvT[s][r] = mat[s*L + r0 + r];
        }
        __syncthreads();

        // den partials: den[r] = sum_s cvT[s][r]  (replaces rowsum/colsum buffers)
        if (t < 128) {
            int row = t & 15, grp = t >> 4;
            float s = 0.f;
            for (int ss = 0; ss < 16; ++ss) s += cvT[grp*16 + ss][row];
            denred[grp][row] = s;
        }

        const int tr = t & 7, th = t >> 3;   // 2 rows x 4 h per thread, th<25 active
        float acc[2][4], amx[2][4];
#pragma unroll
        for (int rr = 0; rr < 2; ++rr)
#pragma unroll
            for (int qq = 0; qq < 4; ++qq) { acc[rr][qq] = 0.f; amx[rr][qq] = -INFINITY; }
        if (th < 25) {
            for (int s = 0; s < L; ++s) {
                float2 c2 = *(const float2*)&cvT[s][2*tr];
                float4 v4 = *(const float4*)&sv[s][4*th];
                float cs[2] = {c2.x, c2.y};
                float vs[4] = {v4.x, v4.y, v4.z, v4.w};
#pragma unroll
                for (int rr = 0; rr < 2; ++rr)
#pragma unroll
                    for (int qq = 0; qq < 4; ++qq) {
                        float pr = cs[rr] * vs[qq];
                        acc[rr][qq] += pr;
                        amx[rr][qq] = fmaxf(amx[rr][qq], pr);
                    }
            }
        }
        __syncthreads();   // sv/cvT reads done -> region reusable

        // overlay (floats, within old sv region; 12000 <= 12800 floats)
        float* attv = sf;           // [kind2][row16][h100]
        float* v1s  = sf + 3200;    // [row16][h100]
        float* w2l  = sf + 4800;    // [kind2][h100][36] (21 used)
        if (th < 25) {
#pragma unroll
            for (int rr = 0; rr < 2; ++rr) {
                int rloc = 2*tr + rr;
                float dsum = 0.f;
#pragma unroll
                for (int g = 0; g < 8; ++g) dsum += denred[g][rloc];
                float inv = 1.f / fmaxf(dsum, EPSF);
#pragma unroll
                for (int qq = 0; qq < 4; ++qq) {
                    attv[0*1600 + rloc*100 + 4*th + qq] = acc[rr][qq] * inv;
                    attv[1*1600 + rloc*100 + 4*th + qq] = amx[rr][qq];
                }
            }
        }
        for (int e = t; e < 400; e += 256) {
            int row = e / 25, g = e - row*25;
            *(float4*)&v1s[row*100 + 4*g] =
                *(const float4*)(srcI + (size_t)(b*L + r0 + row)*(2*H) + dir*H + 4*g);
        }
        // w^2 tables from params: kind0 (mean) -> params[4+dir], kind1 (max) -> params[6+dir]
        for (int e = t; e < 4200; e += 256) {
            int kind = e >= 2100 ? 1 : 0, r = e - kind*2100;
            int h = r / 21, p = r - h*21;
            float v = 1.f;
            if (p < P) {
                float w = params[((size_t)((4 + kind*2 + dir)*P + p))*H + h];
                v = w*w;
            }
            w2l[kind*3600 + h*36 + p] = v;
        }
        __syncthreads();

        // phase C: 32 tasks (kind2 x row16) x 8 h-strip lanes
        {
            const int task = t >> 3, tt = t & 7;
            const int kind = task >> 4, row = task & 15;
            const int h0 = tt*13, cnt = (tt < 7) ? 13 : 9;
            const float* av  = attv + kind*1600 + row*100;
            const float* v1r = v1s + row*100;
            const float* wk  = w2l + kind*3600;

            float s11[21], s22[21], s12[21];
#pragma unroll
            for (int p = 0; p < 21; ++p) { s11[p] = 0.f; s22[p] = 0.f; s12[p] = 0.f; }
            for (int hh = 0; hh < cnt; ++hh) {
                int h = h0 + hh;
                float a = v1r[h], c = av[h];
                float xx = a*a, yy = c*c, xy = a*c;
                const float* wrow = wk + h*36;
#pragma unroll
                for (int pg = 0; pg < 5; ++pg) {
                    float4 wv = *(const float4*)&wrow[4*pg];
                    float ws[4] = {wv.x, wv.y, wv.z, wv.w};
#pragma unroll
                    for (int q = 0; q < 4; ++q) {
                        int p = 4*pg + q;
                        s11[p] = fmaf(ws[q], xx, s11[p]);
                        s22[p] = fmaf(ws[q], yy, s22[p]);
                        s12[p] = fmaf(ws[q], xy, s12[p]);
                    }
                }
                float w20 = wrow[20];
                s11[20] = fmaf(w20, xx, s11[20]);
                s22[20] = fmaf(w20, yy, s22[20]);
                s12[20] = fmaf(w20, xy, s12[20]);
            }
#pragma unroll
            for (int p = 0; p < 21; ++p) {
#pragma unroll
                for (int d = 1; d < 8; d <<= 1) {
                    s11[p] += __shfl_xor(s11[p], d);
                    s22[p] += __shfl_xor(s22[p], d);
                    s12[p] += __shfl_xor(s12[p], d);
                }
            }
            if (tt == 0) {
                int chb = kind ? (dir ? 189 : 168) : (dir ? 147 : 126);
                float* orow = out + (size_t)side*B*L*CH + (size_t)(b*L + r0 + row)*CH;
#pragma unroll
                for (int p = 0; p < 21; ++p) {
                    float cv = s12[p] / (fmaxf(sqrtf(s11[p]), EPSF) * fmaxf(sqrtf(s22[p]), EPSF));
                    orow[(p == P) ? chb : (chb + 1 + p)] = cv;
                }
            }
        }
        return;
    }

    // ================= point task m0/1 (lastv inline, w^2 from params) =================
    {
        const int idx = k - 1184;
        const int b = idx & 15, side = (idx >> 4) & 1, m = idx >> 5;
        const int i = t & 127, half = t >> 7;
        const int chb = m ? 25 : 4;
        const float* opp = side ? ctx_p : ctx_h;
        const int* omask = side ? mask_p : mask_h;

        int last = 0;
        if (m == 0) {
            int* sm = (int*)smem;
            if (t < 128) sm[t] = omask[b*L + t];
            __syncthreads();
            for (int s = 64; s > 0; s >>= 1) {
                if (t < s) sm[t] += sm[t + s];
                __syncthreads();
            }
            last = sm[0] - 1;
            if (last < 0) last = 0;
            __syncthreads();   // sm region about to be reused as red
        }

        const float* v1p = (side ? ctx_h : ctx_p) + (size_t)(b*L + i)*(2*H) + m*H;
        const float* v2p = (m == 0) ? (opp + (size_t)(b*L + last)*(2*H))
                                    : (opp + (size_t)(b*L + 0)*(2*H) + H);

        float s11[21], s22[21], s12[21];
#pragma unroll
        for (int p = 0; p < 21; ++p) { s11[p] = 0.f; s22[p] = 0.f; s12[p] = 0.f; }
        const int g0 = half ? 13 : 0, g1 = half ? 25 : 13;
        for (int g = g0; g < g1; ++g) {
            float4 x = *(const float4*)(v1p + 4*g);
            float4 y = *(const float4*)(v2p + 4*g);
            float xx[4] = {x.x*x.x, x.y*x.y, x.z*x.z, x.w*x.w};
            float yy[4] = {y.x*y.x, y.y*y.y, y.z*y.z, y.w*y.w};
            float xy[4] = {x.x*y.x, x.y*y.y, x.z*y.z, x.w*y.w};
#pragma unroll
            for (int hh = 0; hh < 4; ++hh) {
                int h = 4*g + hh;
#pragma unroll
                for (int p = 0; p < 21; ++p) {
                    float w2;
                    if (p < P) { float w = params[((size_t)(m*P + p))*H + h]; w2 = w*w; }
                    else w2 = 1.f;
                    s11[p] = fmaf(w2, xx[hh], s11[p]);
                    s22[p] = fmaf(w2, yy[hh], s22[p]);
                    s12[p] = fmaf(w2, xy[hh], s12[p]);
                }
            }
        }
        float* red = (float*)smem;   // [3][21][128]
        if (half) {
#pragma unroll
            for (int p = 0; p < 21; ++p) {
                red[(0*21 + p)*128 + i] = s11[p];
                red[(1*21 + p)*128 + i] = s22[p];
                red[(2*21 + p)*128 + i] = s12[p];
            }
        }
        __syncthreads();
        if (!half) {
            float* orow = out + (size_t)side*B*L*CH + (size_t)(b*L + i)*CH;
#pragma unroll
            for (int p = 0; p < 21; ++p) {
                float a = s11[p] + red[(0*21 + p)*128 + i];
                float c = s22[p] + red[(1*21 + p)*128 + i];
                float d = s12[p] + red[(2*21 + p)*128 + i];
                float cv = d / (fmaxf(sqrtf(a), EPSF) * fmaxf(sqrtf(c), EPSF));
                orow[(p == P) ? chb : (chb + 1 + p)] = cv;
            }
        }
    }
}

extern "C" void kernel_launch(void* const* d_in, const int* in_sizes, int n_in,
                              void* d_out, int out_size, void* d_ws, size_t ws_size,
                              hipStream_t stream) {
    const float* ctx_p  = (const float*)d_in[0];
    const int*   mask_p = (const int*)d_in[1];
    const float* ctx_h  = (const float*)d_in[2];
    const int*   mask_h = (const int*)d_in[3];
    const float* params = (const float*)d_in[4];
    float* out = (float*)d_out;

    float* ws = (float*)d_ws;
    float* cosbuf = ws + OFF_COS;
    float* cosT   = ws + OFF_COST;
    int*   flags  = (int*)(ws + OFF_FLAGS);

    fused_kernel<<<dim3(1248), 256, 0, stream>>>(ctx_p, mask_p, ctx_h, mask_h, params,
                                                 cosbuf, cosT, flags, out);
}